// Round 6
// baseline (351.372 us; speedup 1.0000x reference)
//
#include <hip/hip_runtime.h>
#include <cstdint>
#include <cstddef>

#define BN 4
#define CC 27
#define HH 160
#define WW 160
#define HWp (HH*WW)        // 25600
#define NPIX (BN*HWp)      // 102400
#define DD 768
#define KK 24
#define NT 400             // 64-px tiles per image
#define NTS 8              // tiles per gemm block (K = 512 px)
#define NSP 50             // splits: NT/NTS

// ---- workspace float offsets ----
#define OFF_ACC 0                        // 32 scalars
#define OFF_S1 32                        // B*K*C = 2592
#define OFF_S2 (OFF_S1+2592)
#define OFF_CNT (OFF_S2+2592)            // 96
#define OFF_PP (OFF_CNT+96)              // B*CC*DD = 82944
#define OFF_QP (OFF_PP+82944)
#define OFF_NSQ (OFF_QP+82944)           // NPIX (atomically accumulated)
#define ZERO_N (OFF_NSQ+NPIX)            // zeroed each call
#define OFF_LAB ZERO_N                   // uint8 labels, NPIX bytes
#define OFF_PROBS (OFF_LAB + NPIX/4)     // BN*CC*HWp fp32
#define OFF_FBF (OFF_PROBS + BN*CC*HWp)  // bf16 feats TILED: (b,dt3,T)[256][64] swizzled
#define OFF_WBF (OFF_FBF + (size_t)BN*3*NT*16384/2)  // bf16 W TILED: (b,T)[64][64] swizzled

typedef __attribute__((ext_vector_type(8))) short short8v;
typedef __attribute__((ext_vector_type(4))) float f32x4;

__device__ __forceinline__ float wave_sum(float v) {
#pragma unroll
  for (int o = 32; o > 0; o >>= 1) v += __shfl_down(v, o, 64);
  return v;
}

__device__ __forceinline__ unsigned short f2bf(float x) {
  unsigned u = __builtin_bit_cast(unsigned, x);
  unsigned r = u + 0x7FFFu + ((u >> 16) & 1u);
  return (unsigned short)(r >> 16);
}

__global__ void k_zero(float* __restrict__ w, int n) {
  int i = blockIdx.x * 256 + threadIdx.x;
  if (i < n) w[i] = 0.f;
}

__global__ void k_depth_stats(const float* __restrict__ depth, float* __restrict__ acc) {
  int i = blockIdx.x * 256 + threadIdx.x;
  float g = 0.f;
  if (i < NPIX) {
    int b = i / HWp, r = i % HWp, h = r / WW, w = r % WW;
    const float* dp = depth + b * HWp;
    float d0 = dp[r];
    float gh = (h < HH-1) ? fabsf(dp[r+WW] - d0) : 0.f;
    float gw = (w < WW-1) ? fabsf(dp[r+1] - d0) : 0.f;
    g = gh + gw;
  }
  __shared__ float red;
  if (threadIdx.x == 0) red = 0.f;
  __syncthreads();
  float s = wave_sum(g);
  if ((threadIdx.x & 63) == 0) atomicAdd(&red, s);
  __syncthreads();
  if (threadIdx.x == 0) atomicAdd(&acc[0], red);
}

__global__ void k_labels(const float* __restrict__ cl, unsigned char* __restrict__ lab) {
  int i = blockIdx.x * 256 + threadIdx.x;
  if (i >= NPIX) return;
  int b = i / HWp, r = i % HWp;
  const float* p = cl + (size_t)b * CC * HWp + r;
  float best = p[0]; int bi = 0;
#pragma unroll
  for (int c = 1; c < CC; ++c) {
    float v = p[(size_t)c * HWp];
    if (v > best) { best = v; bi = c; }
  }
  lab[i] = (unsigned char)bi;
}

// fp32 feats -> bf16 TILED/SWIZZLED fbf (256-row tiles), per-pixel norm^2 atomics.
// 16 B/lane reads, 8 B/lane stores.
__global__ void __launch_bounds__(256) k_fconv(const float* __restrict__ feats,
        unsigned short* __restrict__ fbf, float* __restrict__ nsq) {
  int t = threadIdx.x;
  int slab = blockIdx.x;                 // 100 slabs of 1024 px (25 per image)
  int b = slab / (HWp / 1024);
  int px0 = (slab % (HWp / 1024)) * 1024;
  int d0 = blockIdx.y * (DD / 8);        // 8-way d split, 96 rows each
  int p = px0 + 4 * t;
  int T = p >> 6, j = p & 63;
  const float* src = feats + ((size_t)b * DD + d0) * HWp + p;
  float n0 = 0.f, n1 = 0.f, n2 = 0.f, n3 = 0.f;
#pragma unroll 4
  for (int d = 0; d < DD / 8; ++d) {
    int dgl = d0 + d;
    float4 v = *(const float4*)(src + (size_t)d * HWp);
    n0 += v.x * v.x; n1 += v.y * v.y; n2 += v.z * v.z; n3 += v.w * v.w;
    ushort4 h;
    h.x = f2bf(v.x); h.y = f2bf(v.y); h.z = f2bf(v.z); h.w = f2bf(v.w);
    int dt = dgl >> 8, rin = dgl & 255;
    size_t addr = ((size_t)(b * 3 + dt) * NT + T) * 16384 + rin * 64
                + (((j >> 3) ^ (rin & 7)) * 8) + (j & 7);
    *(ushort4*)&fbf[addr] = h;
  }
  atomicAdd(&nsq[b * HWp + p + 0], n0);
  atomicAdd(&nsq[b * HWp + p + 1], n1);
  atomicAdd(&nsq[b * HWp + p + 2], n2);
  atomicAdd(&nsq[b * HWp + p + 3], n3);
}

// per-pixel: softmax stats + distill/bpl/entropy scalars, probs fp32,
// and W tiles (swizzled): row c = bf16(pt), row 32+c = bf16(pt*invnorm)
__global__ void k_main(const float* __restrict__ logits, const float* __restrict__ depth,
                       const unsigned char* __restrict__ lab, const float* __restrict__ nsq,
                       float* __restrict__ probs, unsigned short* __restrict__ wbf,
                       float* __restrict__ acc) {
  int i = blockIdx.x * 256 + threadIdx.x;
  float c_dist = 0.f, c_bnum = 0.f, c_bcnt = 0.f, c_ent = 0.f;
  if (i < NPIX) {
    int b = i / HWp, r = i % HWp, h = r / WW, w = r % WW;
    const float* lg = logits + (size_t)b * CC * HWp + r;
    float x[CC];
    float m = -1e30f;
#pragma unroll
    for (int c = 0; c < CC; ++c) { x[c] = lg[(size_t)c * HWp]; m = fmaxf(m, x[c]); }
    float se = 0.f, sx = 0.f, set = 0.f;
#pragma unroll
    for (int c = 0; c < CC; ++c) {
      se += expf(x[c] - m);
      set += expf(10.f * (x[c] - m));
      sx += x[c];
    }
    float lse = logf(se);
    float inv_set = 1.f / set;
    float invn = 1.f / fmaxf(sqrtf(nsq[i]), 1e-12f);
    int l = lab[i];
    float xl = x[0];
    float ent = 0.f;
    float* pb = probs + (size_t)b * CC * HWp + r;
    int T = r >> 6, j = r & 63;
    unsigned short* wb = wbf + ((size_t)b * NT + T) * 4096;
#pragma unroll
    for (int c = 0; c < CC; ++c) {
      float lp = x[c] - m - lse;
      float p = expf(lp);
      pb[(size_t)c * HWp] = p;
      float ptc = expf(10.f * (x[c] - m)) * inv_set;
      wb[c * 64 + (((j >> 3) ^ (c & 7)) * 8) + (j & 7)] = f2bf(ptc);
      int c2 = 32 + c;
      wb[c2 * 64 + (((j >> 3) ^ (c2 & 7)) * 8) + (j & 7)] = f2bf(ptc * invn);
      ent -= p * lp;
      if (c == l) xl = x[c];
    }
    float nll = m + lse - xl;
    float ce = 0.8f * nll + 0.2f * (m + lse - sx * (1.f / CC));
    float ptf = expf(-ce);
    float wgt = (1.f - ptf) * (1.f - ptf);
    if (l >= 11 && l <= 18) wgt *= 2.f;
    const float* dp = depth + b * HWp;
    float d0 = dp[r];
    float gh = (h < HH-1) ? fabsf(dp[r+WW] - d0) : 0.f;
    float gw = (w < WW-1) ? fabsf(dp[r+1] - d0) : 0.f;
    float gmean = acc[0] * (1.f / NPIX);
    float gnorm = (gh + gw) / (gmean + 1e-6f);
    wgt *= 1.f + 0.1f * fminf(gnorm, 3.f);
    const unsigned char* lb = lab + b * HWp;
    int lL = lb[h*WW + (w>0 ? w-1 : w)];
    int lR = lb[h*WW + (w<WW-1 ? w+1 : w)];
    int lU = lb[(h>0 ? h-1 : h)*WW + w];
    int lD = lb[(h<HH-1 ? h+1 : h)*WW + w];
    float bnd = ((l != lL) | (l != lR) | (l != lU) | (l != lD)) ? 1.f : 0.f;
    c_dist = ce * wgt;
    c_bnum = ce * bnd;
    c_bcnt = bnd;
    c_ent = ent;
  }
  __shared__ float red[4];
  if (threadIdx.x < 4) red[threadIdx.x] = 0.f;
  __syncthreads();
  c_dist = wave_sum(c_dist); c_bnum = wave_sum(c_bnum);
  c_bcnt = wave_sum(c_bcnt); c_ent = wave_sum(c_ent);
  if ((threadIdx.x & 63) == 0) {
    atomicAdd(&red[0], c_dist); atomicAdd(&red[1], c_bnum);
    atomicAdd(&red[2], c_bcnt); atomicAdd(&red[3], c_ent);
  }
  __syncthreads();
  if (threadIdx.x == 0) {
    atomicAdd(&acc[1], red[0]); atomicAdd(&acc[2], red[1]);
    atomicAdd(&acc[3], red[2]); atomicAdd(&acc[4], red[3]);
  }
}

// MFMA GEMM: per block (b, dt in 3, s in 50): [256 d x 64 c'] over 512 px.
// 128 MFMA per barrier phase; DMA staging, double-buffered 80 KB LDS,
// counted vmcnt(10); XCD-swizzled block index; fp32 atomic finalize.
__global__ void __launch_bounds__(256) k_gemm(const unsigned short* __restrict__ fbf,
        const unsigned short* __restrict__ wbf, float* __restrict__ P, float* __restrict__ Q) {
  __shared__ unsigned short As[2][16384];
  __shared__ unsigned short Ws[2][4096];
  int orig = blockIdx.x;
  int bx = (orig & 7) * 75 + (orig >> 3);   // bijective: 600 = 8*75
  int s  = bx % NSP;
  int dt = (bx / NSP) % 3;
  int b  = bx / (NSP * 3);
  int t = threadIdx.x;
  int wave = t >> 6, lane = t & 63;
  int g = lane >> 4, rr = lane & 15;
  f32x4 acc[4][4] = {};
  const unsigned short* Abase = fbf + ((size_t)(b*3+dt)*NT + s*NTS) * 16384;
  const unsigned short* Wbase = wbf + ((size_t)b*NT + s*NTS) * 4096;

#define STAGE(ch, bufi) do { \
    const unsigned short* as_ = Abase + (size_t)(ch) * 16384; \
    const unsigned short* ws_ = Wbase + (size_t)(ch) * 4096; \
    _Pragma("unroll") \
    for (int i_ = 0; i_ < 8; ++i_) { \
      int off_ = (wave*8 + i_) * 512; \
      __builtin_amdgcn_global_load_lds( \
        (const __attribute__((address_space(1))) void*)(as_ + off_ + lane*8), \
        (__attribute__((address_space(3))) void*)&As[bufi][off_], 16, 0, 0); \
    } \
    _Pragma("unroll") \
    for (int i_ = 0; i_ < 2; ++i_) { \
      int off_ = (wave*2 + i_) * 512; \
      __builtin_amdgcn_global_load_lds( \
        (const __attribute__((address_space(1))) void*)(ws_ + off_ + lane*8), \
        (__attribute__((address_space(3))) void*)&Ws[bufi][off_], 16, 0, 0); \
    } \
  } while (0)

  STAGE(0, 0);
  for (int ch = 0; ch < NTS; ++ch) {
    int cur = ch & 1;
    if (ch + 1 < NTS) {
      STAGE(ch + 1, cur ^ 1);
      asm volatile("s_waitcnt vmcnt(10)" ::: "memory");
    } else {
      asm volatile("s_waitcnt vmcnt(0)" ::: "memory");
    }
    __builtin_amdgcn_s_barrier();
    __builtin_amdgcn_sched_barrier(0);
#pragma unroll
    for (int ks = 0; ks < 2; ++ks) {
      short8v a[4], wf[4];
#pragma unroll
      for (int m = 0; m < 4; ++m) {
        int row = wave*64 + m*16 + rr;
        int ck = (ks*4 + g) ^ (row & 7);
        a[m] = *(const short8v*)&As[cur][row*64 + ck*8];
      }
#pragma unroll
      for (int ct = 0; ct < 4; ++ct) {
        int row = ct*16 + rr;
        int ck = (ks*4 + g) ^ (row & 7);
        wf[ct] = *(const short8v*)&Ws[cur][row*64 + ck*8];
      }
#pragma unroll
      for (int m = 0; m < 4; ++m)
#pragma unroll
        for (int ct = 0; ct < 4; ++ct)
          acc[m][ct] = __builtin_amdgcn_mfma_f32_16x16x32_bf16(a[m], wf[ct], acc[m][ct], 0, 0, 0);
    }
    __builtin_amdgcn_sched_barrier(0);
    __builtin_amdgcn_s_barrier();
  }
#undef STAGE
  // epilogue: C/D layout col=lane&15 (c'), row=(lane>>4)*4+reg (d)
#pragma unroll
  for (int m = 0; m < 4; ++m) {
#pragma unroll
    for (int ct = 0; ct < 4; ++ct) {
      int cp = ct * 16 + rr;
#pragma unroll
      for (int rg = 0; rg < 4; ++rg) {
        int d = dt * 256 + wave * 64 + m * 16 + g * 4 + rg;
        float v = acc[m][ct][rg];
        if (cp < CC)
          atomicAdd(&P[((size_t)b * CC + cp) * DD + d], v);
        else if (cp >= 32 && cp < 32 + CC)
          atomicAdd(&Q[((size_t)b * CC + (cp - 32)) * DD + d], v);
      }
    }
  }
}

// fused: depth-alignment + instance-boundary BCE + instance-uniformity histogram
__global__ void k_tail(const float* __restrict__ probs, const float* __restrict__ depth,
                       const int* __restrict__ inst, float* __restrict__ acc,
                       float* __restrict__ s1g, float* __restrict__ s2g,
                       float* __restrict__ cntg) {
  __shared__ float ls1[4][KK*CC], ls2[4][KK*CC], lc[4][KK];
  int t = threadIdx.x; int wv = t >> 6;
  for (int idx = t; idx < 4*KK*CC; idx += 256) { (&ls1[0][0])[idx] = 0.f; (&ls2[0][0])[idx] = 0.f; }
  if (t < 4*KK) (&lc[0][0])[t] = 0.f;
  __syncthreads();
  int i = blockIdx.x * 256 + t;
  int b = i / HWp, r = i % HWp, h = r / WW, w = r % WW;
  const float* P = probs + (size_t)b * CC * HWp + r;
  const int* ip = inst + b * HWp;
  int id = ip[r];
  atomicAdd(&lc[wv][id], 1.f);
  bool hasR = (w < WW-1), hasD = (h < HH-1);
  float sh = 0.f, sv = 0.f, mh = 0.f, mw = 0.f;
#pragma unroll
  for (int c = 0; c < CC; ++c) {
    float p  = P[(size_t)c * HWp];
    atomicAdd(&ls1[wv][id*CC + c], p);
    atomicAdd(&ls2[wv][id*CC + c], p * p);
    float pr = hasR ? P[(size_t)c * HWp + 1]  : p;
    float pd = hasD ? P[(size_t)c * HWp + WW] : p;
    float dr = pr - p, dd = pd - p;
    sh += dr * dr; sv += dd * dd;
    mw = fmaxf(mw, fabsf(dr)); mh = fmaxf(mh, fabsf(dd));
  }
  float aH = 0.f, aV = 0.f, bh = 0.f, bw = 0.f;
  const float* dp = depth + b * HWp;
  float d0 = dp[r];
  if (hasR) {
    float ddh = dp[r+1] - d0;
    aH = expf(-(ddh*ddh) * 200.f) * sh;
    float y = (ip[r+1] != ip[r]) ? 1.f : 0.f;
    float xx = fminf(fmaxf(mw, 1e-6f), 1.f - 1e-6f);
    bw = -(y * logf(xx) + (1.f - y) * log1pf(-xx));
  }
  if (hasD) {
    float ddv = dp[r+WW] - d0;
    aV = expf(-(ddv*ddv) * 200.f) * sv;
    float y = (ip[r+WW] != ip[r]) ? 1.f : 0.f;
    float xx = fminf(fmaxf(mh, 1e-6f), 1.f - 1e-6f);
    bh = -(y * logf(xx) + (1.f - y) * log1pf(-xx));
  }
  __shared__ float red[4];
  if (t < 4) red[t] = 0.f;
  __syncthreads();
  aH = wave_sum(aH); aV = wave_sum(aV); bh = wave_sum(bh); bw = wave_sum(bw);
  if ((t & 63) == 0) {
    atomicAdd(&red[0], aH); atomicAdd(&red[1], aV);
    atomicAdd(&red[2], bh); atomicAdd(&red[3], bw);
  }
  __syncthreads();
  if (t == 0) {
    atomicAdd(&acc[5], red[0]); atomicAdd(&acc[6], red[1]);
    atomicAdd(&acc[7], red[2]); atomicAdd(&acc[8], red[3]);
  }
  for (int idx = t; idx < KK*CC; idx += 256) {
    atomicAdd(&s1g[b*KK*CC + idx], ls1[0][idx]+ls1[1][idx]+ls1[2][idx]+ls1[3][idx]);
    atomicAdd(&s2g[b*KK*CC + idx], ls2[0][idx]+ls2[1][idx]+ls2[2][idx]+ls2[3][idx]);
  }
  if (t < KK) atomicAdd(&cntg[b*KK + t], lc[0][t]+lc[1][t]+lc[2][t]+lc[3][t]);
}

__global__ void k_pfinal(const float* __restrict__ P, const float* __restrict__ Q,
                         float* __restrict__ acc) {
  int bc = blockIdx.x;   // b*CC + c
  float dot = 0.f, nsq = 0.f;
  for (int d = threadIdx.x; d < DD; d += 256) {
    float p = P[(size_t)bc * DD + d];
    float q = Q[(size_t)bc * DD + d];
    dot += p * q; nsq += p * p;
  }
  __shared__ float red[2];
  if (threadIdx.x < 2) red[threadIdx.x] = 0.f;
  __syncthreads();
  dot = wave_sum(dot); nsq = wave_sum(nsq);
  if ((threadIdx.x & 63) == 0) { atomicAdd(&red[0], dot); atomicAdd(&red[1], nsq); }
  __syncthreads();
  if (threadIdx.x == 0) atomicAdd(&acc[9], red[0] / fmaxf(sqrtf(red[1]), 1e-12f));
}

__global__ void k_final(const float* __restrict__ s1g, const float* __restrict__ s2g,
                        const float* __restrict__ cntg, const float* __restrict__ acc,
                        float* __restrict__ out) {
  int t = threadIdx.x;
  float vsum = 0.f, vcnt = 0.f;
  if (t < BN*KK) {
    int k = t % KK;
    float count = cntg[t];
    float nc = fmaxf(count, 1.f);
    float var = 0.f;
#pragma unroll
    for (int c = 0; c < CC; ++c) {
      float m1 = s1g[t*CC + c] / nc;
      var += s2g[t*CC + c] / nc - m1 * m1;
    }
    var *= (1.f / CC);
    if (k > 0 && count >= 25.f) { vsum = var; vcnt = 1.f; }
  }
  __shared__ float red[2];
  if (t < 2) red[t] = 0.f;
  __syncthreads();
  vsum = wave_sum(vsum); vcnt = wave_sum(vcnt);
  if ((t & 63) == 0) { atomicAdd(&red[0], vsum); atomicAdd(&red[1], vcnt); }
  __syncthreads();
  if (t == 0) {
    float l_distill = acc[1] * (1.f / NPIX);
    float bcnt = acc[3];
    float l_bpl = (bcnt > 0.f) ? acc[2] / fmaxf(bcnt, 1.f) : 0.f;
    float l_align = acc[5] * (1.f / (BN*HH*(WW-1))) + acc[6] * (1.f / (BN*(HH-1)*WW));
    float l_ent = acc[4] * (1.f / NPIX);
    float l_ib = 0.5f * (acc[7] * (1.f / (BN*(HH-1)*WW)) + acc[8] * (1.f / (BN*HH*(WW-1))));
    float l_proto = -acc[9] * (1.f / NPIX);
    float l_iu = red[0] / fmaxf(red[1], 1.f);
    out[0] = 1.0f*l_distill + 0.5f*l_bpl + 5.0f*l_align + 0.5f*l_proto +
             0.3f*l_ent + 0.5f*l_iu + 0.5f*l_ib;
  }
}

extern "C" void kernel_launch(void* const* d_in, const int* in_sizes, int n_in,
                              void* d_out, int out_size, void* d_ws, size_t ws_size,
                              hipStream_t stream) {
  (void)in_sizes; (void)n_in; (void)out_size; (void)ws_size;
  const float* logits = (const float*)d_in[0];
  const float* cause  = (const float*)d_in[1];
  const float* feats  = (const float*)d_in[2];
  const float* depth  = (const float*)d_in[3];
  const int*   inst   = (const int*)d_in[4];
  float* ws = (float*)d_ws;
  float* acc = ws + OFF_ACC;
  float* s1  = ws + OFF_S1;
  float* s2  = ws + OFF_S2;
  float* cnt = ws + OFF_CNT;
  float* Pg  = ws + OFF_PP;
  float* Qg  = ws + OFF_QP;
  float* nsq = ws + OFF_NSQ;
  unsigned char* lab = (unsigned char*)(ws + OFF_LAB);
  float* probs = ws + OFF_PROBS;
  unsigned short* fbf = (unsigned short*)(ws + OFF_FBF);
  unsigned short* wbf = (unsigned short*)(ws + OFF_WBF);
  float* out = (float*)d_out;

  k_zero<<<(ZERO_N + 255) / 256, 256, 0, stream>>>(ws, ZERO_N);
  k_depth_stats<<<NPIX / 256, 256, 0, stream>>>(depth, acc);
  k_labels<<<NPIX / 256, 256, 0, stream>>>(cause, lab);
  k_fconv<<<dim3(NPIX / 1024, 8), 256, 0, stream>>>(feats, fbf, nsq);
  k_main<<<NPIX / 256, 256, 0, stream>>>(logits, depth, lab, nsq, probs, wbf, acc);
  k_gemm<<<BN * 3 * NSP, 256, 0, stream>>>(fbf, wbf, Pg, Qg);
  k_tail<<<NPIX / 256, 256, 0, stream>>>(probs, depth, inst, acc, s1, s2, cnt);
  k_pfinal<<<BN * CC, 256, 0, stream>>>(Pg, Qg, acc);
  k_final<<<1, 256, 0, stream>>>(s1, s2, cnt, acc, out);
}

// Round 7
// 247.827 us; speedup vs baseline: 1.4178x; 1.4178x over previous
//
#include <hip/hip_runtime.h>
#include <cstdint>
#include <cstddef>

#define BN 4
#define CC 27
#define HH 160
#define WW 160
#define HWp (HH*WW)        // 25600
#define NPIX (BN*HWp)      // 102400
#define DD 768
#define KK 24
#define NT 400             // 64-px tiles per image
#define NTS 25             // tiles (chunks) per gemm block: K = 1600 px
#define NSP 16             // splits: NT/NTS

// ---- workspace float offsets ----
#define OFF_ACC 0                        // 32 scalars
#define OFF_S1 32                        // B*K*C = 2592
#define OFF_S2 (OFF_S1+2592)
#define OFF_CNT (OFF_S2+2592)            // 96
#define OFF_NSQ (OFF_CNT+96)             // NPIX (atomically accumulated)
#define ZERO_N (OFF_NSQ+NPIX)            // zeroed each call
#define OFF_LAB ZERO_N                   // uint8 labels, NPIX bytes
#define OFF_PROBS (OFF_LAB + NPIX/4)     // BN*CC*HWp fp32
#define OFF_PP (OFF_PROBS + BN*CC*HWp)   // NSP*BN*CC*DD partials (P)
#define OFF_QP (OFF_PP + NSP*BN*CC*DD)   // NSP*BN*CC*DD partials (Q)
#define OFF_FBF (OFF_QP + NSP*BN*CC*DD)  // bf16 feats TILED: (b,dt6,T)[128][64] swizzled
#define OFF_WBF (OFF_FBF + (size_t)BN*6*NT*8192/2)  // bf16 W TILED: (b,T)[64][64] swizzled

typedef __attribute__((ext_vector_type(8))) short short8v;
typedef __attribute__((ext_vector_type(4))) float f32x4;

__device__ __forceinline__ float wave_sum(float v) {
#pragma unroll
  for (int o = 32; o > 0; o >>= 1) v += __shfl_down(v, o, 64);
  return v;
}

__device__ __forceinline__ unsigned short f2bf(float x) {
  unsigned u = __builtin_bit_cast(unsigned, x);
  unsigned r = u + 0x7FFFu + ((u >> 16) & 1u);
  return (unsigned short)(r >> 16);
}

__global__ void k_zero(float* __restrict__ w, int n) {
  int i = blockIdx.x * 256 + threadIdx.x;
  if (i < n) w[i] = 0.f;
}

__global__ void k_depth_stats(const float* __restrict__ depth, float* __restrict__ acc) {
  int i = blockIdx.x * 256 + threadIdx.x;
  float g = 0.f;
  if (i < NPIX) {
    int b = i / HWp, r = i % HWp, h = r / WW, w = r % WW;
    const float* dp = depth + b * HWp;
    float d0 = dp[r];
    float gh = (h < HH-1) ? fabsf(dp[r+WW] - d0) : 0.f;
    float gw = (w < WW-1) ? fabsf(dp[r+1] - d0) : 0.f;
    g = gh + gw;
  }
  __shared__ float red;
  if (threadIdx.x == 0) red = 0.f;
  __syncthreads();
  float s = wave_sum(g);
  if ((threadIdx.x & 63) == 0) atomicAdd(&red, s);
  __syncthreads();
  if (threadIdx.x == 0) atomicAdd(&acc[0], red);
}

__global__ void k_labels(const float* __restrict__ cl, unsigned char* __restrict__ lab) {
  int i = blockIdx.x * 256 + threadIdx.x;
  if (i >= NPIX) return;
  int b = i / HWp, r = i % HWp;
  const float* p = cl + (size_t)b * CC * HWp + r;
  float best = p[0]; int bi = 0;
#pragma unroll
  for (int c = 1; c < CC; ++c) {
    float v = p[(size_t)c * HWp];
    if (v > best) { best = v; bi = c; }
  }
  lab[i] = (unsigned char)bi;
}

// fp32 feats -> bf16 TILED/SWIZZLED fbf (128-row tiles), per-pixel norm^2 atomics.
__global__ void __launch_bounds__(256) k_fconv(const float* __restrict__ feats,
        unsigned short* __restrict__ fbf, float* __restrict__ nsq) {
  int t = threadIdx.x;
  int slab = blockIdx.x;                 // 100 slabs of 1024 px (25 per image)
  int b = slab / (HWp / 1024);
  int px0 = (slab % (HWp / 1024)) * 1024;
  int d0 = blockIdx.y * (DD / 8);        // 8-way d split, 96 rows each
  int p = px0 + 4 * t;
  int T = p >> 6, j = p & 63;
  const float* src = feats + ((size_t)b * DD + d0) * HWp + p;
  float n0 = 0.f, n1 = 0.f, n2 = 0.f, n3 = 0.f;
#pragma unroll 4
  for (int d = 0; d < DD / 8; ++d) {
    int dgl = d0 + d;
    float4 v = *(const float4*)(src + (size_t)d * HWp);
    n0 += v.x * v.x; n1 += v.y * v.y; n2 += v.z * v.z; n3 += v.w * v.w;
    ushort4 h;
    h.x = f2bf(v.x); h.y = f2bf(v.y); h.z = f2bf(v.z); h.w = f2bf(v.w);
    int dt = dgl >> 7, rin = dgl & 127;
    size_t addr = ((size_t)(b * 6 + dt) * NT + T) * 8192 + rin * 64
                + (((j >> 3) ^ (rin & 7)) * 8) + (j & 7);
    *(ushort4*)&fbf[addr] = h;
  }
  atomicAdd(&nsq[b * HWp + p + 0], n0);
  atomicAdd(&nsq[b * HWp + p + 1], n1);
  atomicAdd(&nsq[b * HWp + p + 2], n2);
  atomicAdd(&nsq[b * HWp + p + 3], n3);
}

// per-pixel: softmax stats + distill/bpl/entropy scalars, probs fp32,
// and W tiles (swizzled): row c = bf16(pt), row 32+c = bf16(pt*invnorm)
__global__ void k_main(const float* __restrict__ logits, const float* __restrict__ depth,
                       const unsigned char* __restrict__ lab, const float* __restrict__ nsq,
                       float* __restrict__ probs, unsigned short* __restrict__ wbf,
                       float* __restrict__ acc) {
  int i = blockIdx.x * 256 + threadIdx.x;
  float c_dist = 0.f, c_bnum = 0.f, c_bcnt = 0.f, c_ent = 0.f;
  if (i < NPIX) {
    int b = i / HWp, r = i % HWp, h = r / WW, w = r % WW;
    const float* lg = logits + (size_t)b * CC * HWp + r;
    float x[CC];
    float m = -1e30f;
#pragma unroll
    for (int c = 0; c < CC; ++c) { x[c] = lg[(size_t)c * HWp]; m = fmaxf(m, x[c]); }
    float se = 0.f, sx = 0.f, set = 0.f;
#pragma unroll
    for (int c = 0; c < CC; ++c) {
      se += expf(x[c] - m);
      set += expf(10.f * (x[c] - m));
      sx += x[c];
    }
    float lse = logf(se);
    float inv_set = 1.f / set;
    float invn = 1.f / fmaxf(sqrtf(nsq[i]), 1e-12f);
    int l = lab[i];
    float xl = x[0];
    float ent = 0.f;
    float* pb = probs + (size_t)b * CC * HWp + r;
    int T = r >> 6, j = r & 63;
    unsigned short* wb = wbf + ((size_t)b * NT + T) * 4096;
#pragma unroll
    for (int c = 0; c < CC; ++c) {
      float lp = x[c] - m - lse;
      float p = expf(lp);
      pb[(size_t)c * HWp] = p;
      float ptc = expf(10.f * (x[c] - m)) * inv_set;
      wb[c * 64 + (((j >> 3) ^ (c & 7)) * 8) + (j & 7)] = f2bf(ptc);
      int c2 = 32 + c;
      wb[c2 * 64 + (((j >> 3) ^ (c2 & 7)) * 8) + (j & 7)] = f2bf(ptc * invn);
      ent -= p * lp;
      if (c == l) xl = x[c];
    }
    float nll = m + lse - xl;
    float ce = 0.8f * nll + 0.2f * (m + lse - sx * (1.f / CC));
    float ptf = expf(-ce);
    float wgt = (1.f - ptf) * (1.f - ptf);
    if (l >= 11 && l <= 18) wgt *= 2.f;
    const float* dp = depth + b * HWp;
    float d0 = dp[r];
    float gh = (h < HH-1) ? fabsf(dp[r+WW] - d0) : 0.f;
    float gw = (w < WW-1) ? fabsf(dp[r+1] - d0) : 0.f;
    float gmean = acc[0] * (1.f / NPIX);
    float gnorm = (gh + gw) / (gmean + 1e-6f);
    wgt *= 1.f + 0.1f * fminf(gnorm, 3.f);
    const unsigned char* lb = lab + b * HWp;
    int lL = lb[h*WW + (w>0 ? w-1 : w)];
    int lR = lb[h*WW + (w<WW-1 ? w+1 : w)];
    int lU = lb[(h>0 ? h-1 : h)*WW + w];
    int lD = lb[(h<HH-1 ? h+1 : h)*WW + w];
    float bnd = ((l != lL) | (l != lR) | (l != lU) | (l != lD)) ? 1.f : 0.f;
    c_dist = ce * wgt;
    c_bnum = ce * bnd;
    c_bcnt = bnd;
    c_ent = ent;
  }
  __shared__ float red[4];
  if (threadIdx.x < 4) red[threadIdx.x] = 0.f;
  __syncthreads();
  c_dist = wave_sum(c_dist); c_bnum = wave_sum(c_bnum);
  c_bcnt = wave_sum(c_bcnt); c_ent = wave_sum(c_ent);
  if ((threadIdx.x & 63) == 0) {
    atomicAdd(&red[0], c_dist); atomicAdd(&red[1], c_bnum);
    atomicAdd(&red[2], c_bcnt); atomicAdd(&red[3], c_ent);
  }
  __syncthreads();
  if (threadIdx.x == 0) {
    atomicAdd(&acc[1], red[0]); atomicAdd(&acc[2], red[1]);
    atomicAdd(&acc[3], red[2]); atomicAdd(&acc[4], red[3]);
  }
}

// MFMA GEMM: per block (b, dt in 6, s in 16): [128 d x 64 c'] over 1600 px.
// Triple-buffered DMA staging (vmcnt(12), 2-chunk lookahead), 16 MFMA/chunk/wave,
// ATOMIC-FREE epilogue: coalesced float4 stores to per-split partial buffers.
__global__ void __launch_bounds__(256) k_gemm(const unsigned short* __restrict__ fbf,
        const unsigned short* __restrict__ wbf,
        float* __restrict__ Pp, float* __restrict__ Qp) {
  __shared__ unsigned short As[3][8192];
  __shared__ unsigned short Ws[3][4096];
  int orig = blockIdx.x;
  int bx = (orig & 7) * 48 + (orig >> 3);   // bijective: 384 = 8*48
  int s  = bx % NSP;
  int dt = (bx / NSP) % 6;
  int b  = bx / (NSP * 6);
  int t = threadIdx.x;
  int wave = t >> 6, lane = t & 63;
  int g = lane >> 4, rr = lane & 15;
  f32x4 acc[2][4] = {};
  const unsigned short* Abase = fbf + ((size_t)(b*6+dt)*NT + s*NTS) * 8192;
  const unsigned short* Wbase = wbf + ((size_t)b*NT + s*NTS) * 4096;

#define STAGE(ch, bufi) do { \
    const unsigned short* as_ = Abase + (size_t)(ch) * 8192; \
    const unsigned short* ws_ = Wbase + (size_t)(ch) * 4096; \
    _Pragma("unroll") \
    for (int i_ = 0; i_ < 4; ++i_) { \
      int off_ = (wave*4 + i_) * 512; \
      __builtin_amdgcn_global_load_lds( \
        (const __attribute__((address_space(1))) void*)(as_ + off_ + lane*8), \
        (__attribute__((address_space(3))) void*)&As[bufi][off_], 16, 0, 0); \
    } \
    _Pragma("unroll") \
    for (int i_ = 0; i_ < 2; ++i_) { \
      int off_ = (wave*2 + i_) * 512; \
      __builtin_amdgcn_global_load_lds( \
        (const __attribute__((address_space(1))) void*)(ws_ + off_ + lane*8), \
        (__attribute__((address_space(3))) void*)&Ws[bufi][off_], 16, 0, 0); \
    } \
  } while (0)

  STAGE(0, 0);
  STAGE(1, 1);
  int cur = 0;
  for (int ch = 0; ch < NTS; ++ch) {
    if (ch + 2 < NTS) {
      STAGE(ch + 2, (cur + 2) % 3);
      asm volatile("s_waitcnt vmcnt(12)" ::: "memory");
    } else if (ch + 1 < NTS) {
      asm volatile("s_waitcnt vmcnt(6)" ::: "memory");
    } else {
      asm volatile("s_waitcnt vmcnt(0)" ::: "memory");
    }
    __builtin_amdgcn_s_barrier();
    __builtin_amdgcn_sched_barrier(0);
#pragma unroll
    for (int ks = 0; ks < 2; ++ks) {
      short8v a[2], wf[4];
#pragma unroll
      for (int dd = 0; dd < 2; ++dd) {
        int row = (wave*2 + dd)*16 + rr;
        int ck = (ks*4 + g) ^ (row & 7);
        a[dd] = *(const short8v*)&As[cur][row*64 + ck*8];
      }
#pragma unroll
      for (int ct = 0; ct < 4; ++ct) {
        int row = ct*16 + rr;
        int ck = (ks*4 + g) ^ (row & 7);
        wf[ct] = *(const short8v*)&Ws[cur][row*64 + ck*8];
      }
#pragma unroll
      for (int dd = 0; dd < 2; ++dd)
#pragma unroll
        for (int ct = 0; ct < 4; ++ct)
          acc[dd][ct] = __builtin_amdgcn_mfma_f32_16x16x32_bf16(a[dd], wf[ct], acc[dd][ct], 0, 0, 0);
    }
    __builtin_amdgcn_sched_barrier(0);
    __builtin_amdgcn_s_barrier();
    cur = (cur + 1) % 3;
  }
#undef STAGE
  // epilogue: C/D layout col=lane&15 (c'), row=(lane>>4)*4+reg (d).
  // Non-atomic float4 stores to partials Pp/Qp[s][b][27][768].
#pragma unroll
  for (int dd = 0; dd < 2; ++dd) {
#pragma unroll
    for (int ct = 0; ct < 4; ++ct) {
      int cp = ct * 16 + rr;
      int d = dt * 128 + (wave * 2 + dd) * 16 + g * 4;
      f32x4 v = acc[dd][ct];
      if (cp < CC)
        *(f32x4*)&Pp[(((size_t)s * BN + b) * CC + cp) * DD + d] = v;
      else if (cp >= 32 && cp < 32 + CC)
        *(f32x4*)&Qp[(((size_t)s * BN + b) * CC + (cp - 32)) * DD + d] = v;
    }
  }
}

// fused: depth-alignment + instance-boundary BCE + instance-uniformity histogram
__global__ void k_tail(const float* __restrict__ probs, const float* __restrict__ depth,
                       const int* __restrict__ inst, float* __restrict__ acc,
                       float* __restrict__ s1g, float* __restrict__ s2g,
                       float* __restrict__ cntg) {
  __shared__ float ls1[4][KK*CC], ls2[4][KK*CC], lc[4][KK];
  int t = threadIdx.x; int wv = t >> 6;
  for (int idx = t; idx < 4*KK*CC; idx += 256) { (&ls1[0][0])[idx] = 0.f; (&ls2[0][0])[idx] = 0.f; }
  if (t < 4*KK) (&lc[0][0])[t] = 0.f;
  __syncthreads();
  int i = blockIdx.x * 256 + t;
  int b = i / HWp, r = i % HWp, h = r / WW, w = r % WW;
  const float* P = probs + (size_t)b * CC * HWp + r;
  const int* ip = inst + b * HWp;
  int id = ip[r];
  atomicAdd(&lc[wv][id], 1.f);
  bool hasR = (w < WW-1), hasD = (h < HH-1);
  float sh = 0.f, sv = 0.f, mh = 0.f, mw = 0.f;
#pragma unroll
  for (int c = 0; c < CC; ++c) {
    float p  = P[(size_t)c * HWp];
    atomicAdd(&ls1[wv][id*CC + c], p);
    atomicAdd(&ls2[wv][id*CC + c], p * p);
    float pr = hasR ? P[(size_t)c * HWp + 1]  : p;
    float pd = hasD ? P[(size_t)c * HWp + WW] : p;
    float dr = pr - p, dd = pd - p;
    sh += dr * dr; sv += dd * dd;
    mw = fmaxf(mw, fabsf(dr)); mh = fmaxf(mh, fabsf(dd));
  }
  float aH = 0.f, aV = 0.f, bh = 0.f, bw = 0.f;
  const float* dp = depth + b * HWp;
  float d0 = dp[r];
  if (hasR) {
    float ddh = dp[r+1] - d0;
    aH = expf(-(ddh*ddh) * 200.f) * sh;
    float y = (ip[r+1] != ip[r]) ? 1.f : 0.f;
    float xx = fminf(fmaxf(mw, 1e-6f), 1.f - 1e-6f);
    bw = -(y * logf(xx) + (1.f - y) * log1pf(-xx));
  }
  if (hasD) {
    float ddv = dp[r+WW] - d0;
    aV = expf(-(ddv*ddv) * 200.f) * sv;
    float y = (ip[r+WW] != ip[r]) ? 1.f : 0.f;
    float xx = fminf(fmaxf(mh, 1e-6f), 1.f - 1e-6f);
    bh = -(y * logf(xx) + (1.f - y) * log1pf(-xx));
  }
  __shared__ float red[4];
  if (t < 4) red[t] = 0.f;
  __syncthreads();
  aH = wave_sum(aH); aV = wave_sum(aV); bh = wave_sum(bh); bw = wave_sum(bw);
  if ((t & 63) == 0) {
    atomicAdd(&red[0], aH); atomicAdd(&red[1], aV);
    atomicAdd(&red[2], bh); atomicAdd(&red[3], bw);
  }
  __syncthreads();
  if (t == 0) {
    atomicAdd(&acc[5], red[0]); atomicAdd(&acc[6], red[1]);
    atomicAdd(&acc[7], red[2]); atomicAdd(&acc[8], red[3]);
  }
  for (int idx = t; idx < KK*CC; idx += 256) {
    atomicAdd(&s1g[b*KK*CC + idx], ls1[0][idx]+ls1[1][idx]+ls1[2][idx]+ls1[3][idx]);
    atomicAdd(&s2g[b*KK*CC + idx], ls2[0][idx]+ls2[1][idx]+ls2[2][idx]+ls2[3][idx]);
  }
  if (t < KK) atomicAdd(&cntg[b*KK + t], lc[0][t]+lc[1][t]+lc[2][t]+lc[3][t]);
}

__global__ void k_pfinal(const float* __restrict__ Pp, const float* __restrict__ Qp,
                         float* __restrict__ acc) {
  int bc = blockIdx.x;   // b*CC + c
  int b = bc / CC, c = bc % CC;
  float dot = 0.f, nsq = 0.f;
  for (int d = threadIdx.x; d < DD; d += 256) {
    float p = 0.f, q = 0.f;
#pragma unroll
    for (int s = 0; s < NSP; ++s) {
      size_t off = (((size_t)s * BN + b) * CC + c) * DD + d;
      p += Pp[off]; q += Qp[off];
    }
    dot += p * q; nsq += p * p;
  }
  __shared__ float red[2];
  if (threadIdx.x < 2) red[threadIdx.x] = 0.f;
  __syncthreads();
  dot = wave_sum(dot); nsq = wave_sum(nsq);
  if ((threadIdx.x & 63) == 0) { atomicAdd(&red[0], dot); atomicAdd(&red[1], nsq); }
  __syncthreads();
  if (threadIdx.x == 0) atomicAdd(&acc[9], red[0] / fmaxf(sqrtf(red[1]), 1e-12f));
}

__global__ void k_final(const float* __restrict__ s1g, const float* __restrict__ s2g,
                        const float* __restrict__ cntg, const float* __restrict__ acc,
                        float* __restrict__ out) {
  int t = threadIdx.x;
  float vsum = 0.f, vcnt = 0.f;
  if (t < BN*KK) {
    int k = t % KK;
    float count = cntg[t];
    float nc = fmaxf(count, 1.f);
    float var = 0.f;
#pragma unroll
    for (int c = 0; c < CC; ++c) {
      float m1 = s1g[t*CC + c] / nc;
      var += s2g[t*CC + c] / nc - m1 * m1;
    }
    var *= (1.f / CC);
    if (k > 0 && count >= 25.f) { vsum = var; vcnt = 1.f; }
  }
  __shared__ float red[2];
  if (t < 2) red[t] = 0.f;
  __syncthreads();
  vsum = wave_sum(vsum); vcnt = wave_sum(vcnt);
  if ((t & 63) == 0) { atomicAdd(&red[0], vsum); atomicAdd(&red[1], vcnt); }
  __syncthreads();
  if (t == 0) {
    float l_distill = acc[1] * (1.f / NPIX);
    float bcnt = acc[3];
    float l_bpl = (bcnt > 0.f) ? acc[2] / fmaxf(bcnt, 1.f) : 0.f;
    float l_align = acc[5] * (1.f / (BN*HH*(WW-1))) + acc[6] * (1.f / (BN*(HH-1)*WW));
    float l_ent = acc[4] * (1.f / NPIX);
    float l_ib = 0.5f * (acc[7] * (1.f / (BN*(HH-1)*WW)) + acc[8] * (1.f / (BN*HH*(WW-1))));
    float l_proto = -acc[9] * (1.f / NPIX);
    float l_iu = red[0] / fmaxf(red[1], 1.f);
    out[0] = 1.0f*l_distill + 0.5f*l_bpl + 5.0f*l_align + 0.5f*l_proto +
             0.3f*l_ent + 0.5f*l_iu + 0.5f*l_ib;
  }
}

extern "C" void kernel_launch(void* const* d_in, const int* in_sizes, int n_in,
                              void* d_out, int out_size, void* d_ws, size_t ws_size,
                              hipStream_t stream) {
  (void)in_sizes; (void)n_in; (void)out_size; (void)ws_size;
  const float* logits = (const float*)d_in[0];
  const float* cause  = (const float*)d_in[1];
  const float* feats  = (const float*)d_in[2];
  const float* depth  = (const float*)d_in[3];
  const int*   inst   = (const int*)d_in[4];
  float* ws = (float*)d_ws;
  float* acc = ws + OFF_ACC;
  float* s1  = ws + OFF_S1;
  float* s2  = ws + OFF_S2;
  float* cnt = ws + OFF_CNT;
  float* nsq = ws + OFF_NSQ;
  float* Pp  = ws + OFF_PP;
  float* Qp  = ws + OFF_QP;
  unsigned char* lab = (unsigned char*)(ws + OFF_LAB);
  float* probs = ws + OFF_PROBS;
  unsigned short* fbf = (unsigned short*)(ws + OFF_FBF);
  unsigned short* wbf = (unsigned short*)(ws + OFF_WBF);
  float* out = (float*)d_out;

  k_zero<<<(ZERO_N + 255) / 256, 256, 0, stream>>>(ws, ZERO_N);
  k_depth_stats<<<NPIX / 256, 256, 0, stream>>>(depth, acc);
  k_labels<<<NPIX / 256, 256, 0, stream>>>(cause, lab);
  k_fconv<<<dim3(NPIX / 1024, 8), 256, 0, stream>>>(feats, fbf, nsq);
  k_main<<<NPIX / 256, 256, 0, stream>>>(logits, depth, lab, nsq, probs, wbf, acc);
  k_gemm<<<BN * 6 * NSP, 256, 0, stream>>>(fbf, wbf, Pp, Qp);
  k_tail<<<NPIX / 256, 256, 0, stream>>>(probs, depth, inst, acc, s1, s2, cnt);
  k_pfinal<<<BN * CC, 256, 0, stream>>>(Pp, Qp, acc);
  k_final<<<1, 256, 0, stream>>>(s1, s2, cnt, acc, out);
}

// Round 8
// 211.246 us; speedup vs baseline: 1.6633x; 1.1732x over previous
//
#include <hip/hip_runtime.h>
#include <cstdint>
#include <cstddef>

#define BN 4
#define CC 27
#define HH 160
#define WW 160
#define HWp (HH*WW)        // 25600
#define NPIX (BN*HWp)      // 102400
#define DD 768
#define KK 24
#define NT 400             // 64-px tiles per image
#define NTS 20             // tiles (chunks) per gemm block: K = 1280 px
#define NSP 20             // splits: NT/NTS
#define NPH (NTS/2)        // 10 two-chunk phases

// ---- workspace float offsets ----
#define OFF_ACC 0                        // 32 scalars
#define OFF_S1 32                        // B*K*C = 2592
#define OFF_S2 (OFF_S1+2592)
#define OFF_CNT (OFF_S2+2592)            // 96
#define OFF_NSQ (OFF_CNT+96)             // NPIX (atomically accumulated)
#define ZERO_N (OFF_NSQ+NPIX)            // zeroed each call
#define OFF_LAB ZERO_N                   // uint8 labels, NPIX bytes
#define OFF_PROBS (OFF_LAB + NPIX/4)     // BN*CC*HWp fp32
#define OFF_PP (OFF_PROBS + BN*CC*HWp)   // NSP*BN*CC*DD partials (P)
#define OFF_QP (OFF_PP + NSP*BN*CC*DD)   // NSP*BN*CC*DD partials (Q)
#define OFF_FBF (OFF_QP + NSP*BN*CC*DD)  // fp8 feats TILED: (b,dt6,T)[128][64] swizzled
#define OFF_WBF (OFF_FBF + (size_t)BN*6*NT*8192/4)  // fp8 W TILED: (b,T)[64][64] swizzled

typedef __attribute__((ext_vector_type(4))) float f32x4;

__device__ __forceinline__ float wave_sum(float v) {
#pragma unroll
  for (int o = 32; o > 0; o >>= 1) v += __shfl_down(v, o, 64);
  return v;
}

__device__ __forceinline__ unsigned char f2fp8(float x) {
  return (unsigned char)(__builtin_amdgcn_cvt_pk_fp8_f32(x, x, 0, false) & 0xff);
}

__global__ void k_zero(float* __restrict__ w, int n) {
  int i = blockIdx.x * 256 + threadIdx.x;
  if (i < n) w[i] = 0.f;
}

// merged: depth-gradient mean + cause argmax labels
__global__ void k_pre(const float* __restrict__ depth, const float* __restrict__ cl,
                      unsigned char* __restrict__ lab, float* __restrict__ acc) {
  int i = blockIdx.x * 256 + threadIdx.x;
  float g = 0.f;
  if (i < NPIX) {
    int b = i / HWp, r = i % HWp, h = r / WW, w = r % WW;
    const float* dp = depth + b * HWp;
    float d0 = dp[r];
    float gh = (h < HH-1) ? fabsf(dp[r+WW] - d0) : 0.f;
    float gw = (w < WW-1) ? fabsf(dp[r+1] - d0) : 0.f;
    g = gh + gw;
    const float* p = cl + (size_t)b * CC * HWp + r;
    float best = p[0]; int bi = 0;
#pragma unroll
    for (int c = 1; c < CC; ++c) {
      float v = p[(size_t)c * HWp];
      if (v > best) { best = v; bi = c; }
    }
    lab[i] = (unsigned char)bi;
  }
  __shared__ float red;
  if (threadIdx.x == 0) red = 0.f;
  __syncthreads();
  float s = wave_sum(g);
  if ((threadIdx.x & 63) == 0) atomicAdd(&red, s);
  __syncthreads();
  if (threadIdx.x == 0) atomicAdd(&acc[0], red);
}

// fp32 feats -> fp8 TILED/SWIZZLED fbf (128-row tiles), per-pixel norm^2 atomics.
__global__ void __launch_bounds__(256) k_fconv(const float* __restrict__ feats,
        unsigned char* __restrict__ fbf, float* __restrict__ nsq) {
  int t = threadIdx.x;
  int slab = blockIdx.x;                 // 100 slabs of 1024 px (25 per image)
  int b = slab / (HWp / 1024);
  int px0 = (slab % (HWp / 1024)) * 1024;
  int d0 = blockIdx.y * (DD / 8);        // 8-way d split, 96 rows each
  int p = px0 + 4 * t;
  int T = p >> 6, j = p & 63;
  const float* src = feats + ((size_t)b * DD + d0) * HWp + p;
  float n0 = 0.f, n1 = 0.f, n2 = 0.f, n3 = 0.f;
#pragma unroll 4
  for (int d = 0; d < DD / 8; ++d) {
    int dgl = d0 + d;
    float4 v = *(const float4*)(src + (size_t)d * HWp);
    n0 += v.x * v.x; n1 += v.y * v.y; n2 += v.z * v.z; n3 += v.w * v.w;
    int pk = __builtin_amdgcn_cvt_pk_fp8_f32(v.x, v.y, 0, false);
    pk = __builtin_amdgcn_cvt_pk_fp8_f32(v.z, v.w, pk, true);
    int dt = dgl >> 7, rin = dgl & 127;
    size_t addr = ((size_t)(b * 6 + dt) * NT + T) * 8192 + rin * 64
                + (((j >> 3) ^ (rin & 7)) * 8) + (j & 7);
    *(int*)&fbf[addr] = pk;
  }
  atomicAdd(&nsq[b * HWp + p + 0], n0);
  atomicAdd(&nsq[b * HWp + p + 1], n1);
  atomicAdd(&nsq[b * HWp + p + 2], n2);
  atomicAdd(&nsq[b * HWp + p + 3], n3);
}

// per-pixel: softmax stats + distill/bpl/entropy scalars, probs fp32,
// and fp8 W tiles (swizzled): row c = pt, row 32+c = pt*invnorm
__global__ void k_main(const float* __restrict__ logits, const float* __restrict__ depth,
                       const unsigned char* __restrict__ lab, const float* __restrict__ nsq,
                       float* __restrict__ probs, unsigned char* __restrict__ wbf,
                       float* __restrict__ acc) {
  int i = blockIdx.x * 256 + threadIdx.x;
  float c_dist = 0.f, c_bnum = 0.f, c_bcnt = 0.f, c_ent = 0.f;
  if (i < NPIX) {
    int b = i / HWp, r = i % HWp, h = r / WW, w = r % WW;
    const float* lg = logits + (size_t)b * CC * HWp + r;
    float x[CC];
    float m = -1e30f;
#pragma unroll
    for (int c = 0; c < CC; ++c) { x[c] = lg[(size_t)c * HWp]; m = fmaxf(m, x[c]); }
    float se = 0.f, sx = 0.f, set = 0.f;
#pragma unroll
    for (int c = 0; c < CC; ++c) {
      se += expf(x[c] - m);
      set += expf(10.f * (x[c] - m));
      sx += x[c];
    }
    float lse = logf(se);
    float inv_set = 1.f / set;
    float invn = 1.f / fmaxf(sqrtf(nsq[i]), 1e-12f);
    int l = lab[i];
    float xl = x[0];
    float ent = 0.f;
    float* pb = probs + (size_t)b * CC * HWp + r;
    int T = r >> 6, j = r & 63;
    unsigned char* wb = wbf + ((size_t)b * NT + T) * 4096;
#pragma unroll
    for (int c = 0; c < CC; ++c) {
      float lp = x[c] - m - lse;
      float p = expf(lp);
      pb[(size_t)c * HWp] = p;
      float ptc = expf(10.f * (x[c] - m)) * inv_set;
      wb[c * 64 + (((j >> 3) ^ (c & 7)) * 8) + (j & 7)] = f2fp8(ptc);
      int c2 = 32 + c;
      wb[c2 * 64 + (((j >> 3) ^ (c2 & 7)) * 8) + (j & 7)] = f2fp8(ptc * invn);
      ent -= p * lp;
      if (c == l) xl = x[c];
    }
    float nll = m + lse - xl;
    float ce = 0.8f * nll + 0.2f * (m + lse - sx * (1.f / CC));
    float ptf = expf(-ce);
    float wgt = (1.f - ptf) * (1.f - ptf);
    if (l >= 11 && l <= 18) wgt *= 2.f;
    const float* dp = depth + b * HWp;
    float d0 = dp[r];
    float gh = (h < HH-1) ? fabsf(dp[r+WW] - d0) : 0.f;
    float gw = (w < WW-1) ? fabsf(dp[r+1] - d0) : 0.f;
    float gmean = acc[0] * (1.f / NPIX);
    float gnorm = (gh + gw) / (gmean + 1e-6f);
    wgt *= 1.f + 0.1f * fminf(gnorm, 3.f);
    const unsigned char* lb = lab + b * HWp;
    int lL = lb[h*WW + (w>0 ? w-1 : w)];
    int lR = lb[h*WW + (w<WW-1 ? w+1 : w)];
    int lU = lb[(h>0 ? h-1 : h)*WW + w];
    int lD = lb[(h<HH-1 ? h+1 : h)*WW + w];
    float bnd = ((l != lL) | (l != lR) | (l != lU) | (l != lD)) ? 1.f : 0.f;
    c_dist = ce * wgt;
    c_bnum = ce * bnd;
    c_bcnt = bnd;
    c_ent = ent;
  }
  __shared__ float red[4];
  if (threadIdx.x < 4) red[threadIdx.x] = 0.f;
  __syncthreads();
  c_dist = wave_sum(c_dist); c_bnum = wave_sum(c_bnum);
  c_bcnt = wave_sum(c_bcnt); c_ent = wave_sum(c_ent);
  if ((threadIdx.x & 63) == 0) {
    atomicAdd(&red[0], c_dist); atomicAdd(&red[1], c_bnum);
    atomicAdd(&red[2], c_bcnt); atomicAdd(&red[3], c_ent);
  }
  __syncthreads();
  if (threadIdx.x == 0) {
    atomicAdd(&acc[1], red[0]); atomicAdd(&acc[2], red[1]);
    atomicAdd(&acc[3], red[2]); atomicAdd(&acc[4], red[3]);
  }
}

// fp8 MFMA GEMM: per block (b, dt in 6, s in 20): [128 d x 64 c'] over 1280 px.
// Two-chunk barrier phases (32 MFMA/wave/phase), triple-buffered DMA (vmcnt(12)),
// atomic-free float4 epilogue to per-split partials.
__global__ void __launch_bounds__(256) k_gemm(const unsigned char* __restrict__ fbf,
        const unsigned char* __restrict__ wbf,
        float* __restrict__ Pp, float* __restrict__ Qp) {
  __shared__ __align__(16) unsigned char As[3][2][8192];
  __shared__ __align__(16) unsigned char Ws[3][2][4096];
  int orig = blockIdx.x;
  int bx = (orig & 7) * 60 + (orig >> 3);   // bijective: 480 = 8*60
  int s  = bx % NSP;
  int dt = (bx / NSP) % 6;
  int b  = bx / (NSP * 6);
  int t = threadIdx.x;
  int wave = t >> 6, lane = t & 63;
  int g = lane >> 4, rr = lane & 15;
  f32x4 acc[2][4] = {};
  const unsigned char* Abase = fbf + ((size_t)(b*6+dt)*NT + s*NTS) * 8192;
  const unsigned char* Wbase = wbf + ((size_t)b*NT + s*NTS) * 4096;

#define STAGE2(ph, bufi) do { \
    _Pragma("unroll") \
    for (int c2_ = 0; c2_ < 2; ++c2_) { \
      const unsigned char* as_ = Abase + (size_t)((ph)*2 + c2_) * 8192; \
      const unsigned char* ws_ = Wbase + (size_t)((ph)*2 + c2_) * 4096; \
      _Pragma("unroll") \
      for (int i_ = 0; i_ < 2; ++i_) { \
        int off_ = wave*2048 + i_*1024; \
        __builtin_amdgcn_global_load_lds( \
          (const __attribute__((address_space(1))) void*)(as_ + off_ + lane*16), \
          (__attribute__((address_space(3))) void*)&As[bufi][c2_][off_], 16, 0, 0); \
      } \
      { \
        int off_ = wave*1024; \
        __builtin_amdgcn_global_load_lds( \
          (const __attribute__((address_space(1))) void*)(ws_ + off_ + lane*16), \
          (__attribute__((address_space(3))) void*)&Ws[bufi][c2_][off_], 16, 0, 0); \
      } \
    } \
  } while (0)

  STAGE2(0, 0);
  STAGE2(1, 1);
  int cur = 0;
  for (int ph = 0; ph < NPH; ++ph) {
    if (ph + 2 < NPH) {
      STAGE2(ph + 2, (cur + 2) % 3);
      asm volatile("s_waitcnt vmcnt(12)" ::: "memory");
    } else if (ph + 1 < NPH) {
      asm volatile("s_waitcnt vmcnt(6)" ::: "memory");
    } else {
      asm volatile("s_waitcnt vmcnt(0)" ::: "memory");
    }
    __builtin_amdgcn_s_barrier();
    __builtin_amdgcn_sched_barrier(0);
#pragma unroll
    for (int c2 = 0; c2 < 2; ++c2) {
#pragma unroll
      for (int ks = 0; ks < 2; ++ks) {
        long a[2]; long wf[4];
#pragma unroll
        for (int dd = 0; dd < 2; ++dd) {
          int row = (wave*2 + dd)*16 + rr;
          int ck = (ks*4 + g) ^ (row & 7);
          a[dd] = *(const long*)&As[cur][c2][row*64 + ck*8];
        }
#pragma unroll
        for (int ct = 0; ct < 4; ++ct) {
          int row = ct*16 + rr;
          int ck = (ks*4 + g) ^ (row & 7);
          wf[ct] = *(const long*)&Ws[cur][c2][row*64 + ck*8];
        }
#pragma unroll
        for (int dd = 0; dd < 2; ++dd)
#pragma unroll
          for (int ct = 0; ct < 4; ++ct)
            acc[dd][ct] = __builtin_amdgcn_mfma_f32_16x16x32_fp8_fp8(a[dd], wf[ct], acc[dd][ct], 0, 0, 0);
      }
    }
    __builtin_amdgcn_sched_barrier(0);
    __builtin_amdgcn_s_barrier();
    cur = (cur + 1) % 3;
  }
#undef STAGE2
  // epilogue: C/D layout col=lane&15 (c'), row=(lane>>4)*4+reg (d).
#pragma unroll
  for (int dd = 0; dd < 2; ++dd) {
#pragma unroll
    for (int ct = 0; ct < 4; ++ct) {
      int cp = ct * 16 + rr;
      int d = dt * 128 + (wave * 2 + dd) * 16 + g * 4;
      f32x4 v = acc[dd][ct];
      if (cp < CC)
        *(f32x4*)&Pp[(((size_t)s * BN + b) * CC + cp) * DD + d] = v;
      else if (cp >= 32 && cp < 32 + CC)
        *(f32x4*)&Qp[(((size_t)s * BN + b) * CC + (cp - 32)) * DD + d] = v;
    }
  }
}

// fused: depth-alignment + instance-boundary BCE + instance-uniformity histogram
__global__ void k_tail(const float* __restrict__ probs, const float* __restrict__ depth,
                       const int* __restrict__ inst, float* __restrict__ acc,
                       float* __restrict__ s1g, float* __restrict__ s2g,
                       float* __restrict__ cntg) {
  __shared__ float ls1[4][KK*CC], ls2[4][KK*CC], lc[4][KK];
  int t = threadIdx.x; int wv = t >> 6;
  for (int idx = t; idx < 4*KK*CC; idx += 256) { (&ls1[0][0])[idx] = 0.f; (&ls2[0][0])[idx] = 0.f; }
  if (t < 4*KK) (&lc[0][0])[t] = 0.f;
  __syncthreads();
  int i = blockIdx.x * 256 + t;
  int b = i / HWp, r = i % HWp, h = r / WW, w = r % WW;
  const float* P = probs + (size_t)b * CC * HWp + r;
  const int* ip = inst + b * HWp;
  int id = ip[r];
  atomicAdd(&lc[wv][id], 1.f);
  bool hasR = (w < WW-1), hasD = (h < HH-1);
  float sh = 0.f, sv = 0.f, mh = 0.f, mw = 0.f;
#pragma unroll
  for (int c = 0; c < CC; ++c) {
    float p  = P[(size_t)c * HWp];
    atomicAdd(&ls1[wv][id*CC + c], p);
    atomicAdd(&ls2[wv][id*CC + c], p * p);
    float pr = hasR ? P[(size_t)c * HWp + 1]  : p;
    float pd = hasD ? P[(size_t)c * HWp + WW] : p;
    float dr = pr - p, dd = pd - p;
    sh += dr * dr; sv += dd * dd;
    mw = fmaxf(mw, fabsf(dr)); mh = fmaxf(mh, fabsf(dd));
  }
  float aH = 0.f, aV = 0.f, bh = 0.f, bw = 0.f;
  const float* dp = depth + b * HWp;
  float d0 = dp[r];
  if (hasR) {
    float ddh = dp[r+1] - d0;
    aH = expf(-(ddh*ddh) * 200.f) * sh;
    float y = (ip[r+1] != ip[r]) ? 1.f : 0.f;
    float xx = fminf(fmaxf(mw, 1e-6f), 1.f - 1e-6f);
    bw = -(y * logf(xx) + (1.f - y) * log1pf(-xx));
  }
  if (hasD) {
    float ddv = dp[r+WW] - d0;
    aV = expf(-(ddv*ddv) * 200.f) * sv;
    float y = (ip[r+WW] != ip[r]) ? 1.f : 0.f;
    float xx = fminf(fmaxf(mh, 1e-6f), 1.f - 1e-6f);
    bh = -(y * logf(xx) + (1.f - y) * log1pf(-xx));
  }
  __shared__ float red[4];
  if (t < 4) red[t] = 0.f;
  __syncthreads();
  aH = wave_sum(aH); aV = wave_sum(aV); bh = wave_sum(bh); bw = wave_sum(bw);
  if ((t & 63) == 0) {
    atomicAdd(&red[0], aH); atomicAdd(&red[1], aV);
    atomicAdd(&red[2], bh); atomicAdd(&red[3], bw);
  }
  __syncthreads();
  if (t == 0) {
    atomicAdd(&acc[5], red[0]); atomicAdd(&acc[6], red[1]);
    atomicAdd(&acc[7], red[2]); atomicAdd(&acc[8], red[3]);
  }
  for (int idx = t; idx < KK*CC; idx += 256) {
    atomicAdd(&s1g[b*KK*CC + idx], ls1[0][idx]+ls1[1][idx]+ls1[2][idx]+ls1[3][idx]);
    atomicAdd(&s2g[b*KK*CC + idx], ls2[0][idx]+ls2[1][idx]+ls2[2][idx]+ls2[3][idx]);
  }
  if (t < KK) atomicAdd(&cntg[b*KK + t], lc[0][t]+lc[1][t]+lc[2][t]+lc[3][t]);
}

__global__ void k_pfinal(const float* __restrict__ Pp, const float* __restrict__ Qp,
                         float* __restrict__ acc) {
  int bc = blockIdx.x;   // b*CC + c
  int b = bc / CC, c = bc % CC;
  float dot = 0.f, nsq = 0.f;
  for (int d = threadIdx.x; d < DD; d += 256) {
    float p = 0.f, q = 0.f;
#pragma unroll
    for (int s = 0; s < NSP; ++s) {
      size_t off = (((size_t)s * BN + b) * CC + c) * DD + d;
      p += Pp[off]; q += Qp[off];
    }
    dot += p * q; nsq += p * p;
  }
  __shared__ float red[2];
  if (threadIdx.x < 2) red[threadIdx.x] = 0.f;
  __syncthreads();
  dot = wave_sum(dot); nsq = wave_sum(nsq);
  if ((threadIdx.x & 63) == 0) { atomicAdd(&red[0], dot); atomicAdd(&red[1], nsq); }
  __syncthreads();
  if (threadIdx.x == 0) atomicAdd(&acc[9], red[0] / fmaxf(sqrtf(red[1]), 1e-12f));
}

__global__ void k_final(const float* __restrict__ s1g, const float* __restrict__ s2g,
                        const float* __restrict__ cntg, const float* __restrict__ acc,
                        float* __restrict__ out) {
  int t = threadIdx.x;
  float vsum = 0.f, vcnt = 0.f;
  if (t < BN*KK) {
    int k = t % KK;
    float count = cntg[t];
    float nc = fmaxf(count, 1.f);
    float var = 0.f;
#pragma unroll
    for (int c = 0; c < CC; ++c) {
      float m1 = s1g[t*CC + c] / nc;
      var += s2g[t*CC + c] / nc - m1 * m1;
    }
    var *= (1.f / CC);
    if (k > 0 && count >= 25.f) { vsum = var; vcnt = 1.f; }
  }
  __shared__ float red[2];
  if (t < 2) red[t] = 0.f;
  __syncthreads();
  vsum = wave_sum(vsum); vcnt = wave_sum(vcnt);
  if ((t & 63) == 0) { atomicAdd(&red[0], vsum); atomicAdd(&red[1], vcnt); }
  __syncthreads();
  if (t == 0) {
    float l_distill = acc[1] * (1.f / NPIX);
    float bcnt = acc[3];
    float l_bpl = (bcnt > 0.f) ? acc[2] / fmaxf(bcnt, 1.f) : 0.f;
    float l_align = acc[5] * (1.f / (BN*HH*(WW-1))) + acc[6] * (1.f / (BN*(HH-1)*WW));
    float l_ent = acc[4] * (1.f / NPIX);
    float l_ib = 0.5f * (acc[7] * (1.f / (BN*(HH-1)*WW)) + acc[8] * (1.f / (BN*HH*(WW-1))));
    float l_proto = -acc[9] * (1.f / NPIX);
    float l_iu = red[0] / fmaxf(red[1], 1.f);
    out[0] = 1.0f*l_distill + 0.5f*l_bpl + 5.0f*l_align + 0.5f*l_proto +
             0.3f*l_ent + 0.5f*l_iu + 0.5f*l_ib;
  }
}

extern "C" void kernel_launch(void* const* d_in, const int* in_sizes, int n_in,
                              void* d_out, int out_size, void* d_ws, size_t ws_size,
                              hipStream_t stream) {
  (void)in_sizes; (void)n_in; (void)out_size; (void)ws_size;
  const float* logits = (const float*)d_in[0];
  const float* cause  = (const float*)d_in[1];
  const float* feats  = (const float*)d_in[2];
  const float* depth  = (const float*)d_in[3];
  const int*   inst   = (const int*)d_in[4];
  float* ws = (float*)d_ws;
  float* acc = ws + OFF_ACC;
  float* s1  = ws + OFF_S1;
  float* s2  = ws + OFF_S2;
  float* cnt = ws + OFF_CNT;
  float* nsq = ws + OFF_NSQ;
  float* Pp  = ws + OFF_PP;
  float* Qp  = ws + OFF_QP;
  unsigned char* lab = (unsigned char*)(ws + OFF_LAB);
  float* probs = ws + OFF_PROBS;
  unsigned char* fbf = (unsigned char*)(ws + OFF_FBF);
  unsigned char* wbf = (unsigned char*)(ws + OFF_WBF);
  float* out = (float*)d_out;

  k_zero<<<(ZERO_N + 255) / 256, 256, 0, stream>>>(ws, ZERO_N);
  k_pre<<<NPIX / 256, 256, 0, stream>>>(depth, cause, lab, acc);
  k_fconv<<<dim3(NPIX / 1024, 8), 256, 0, stream>>>(feats, fbf, nsq);
  k_main<<<NPIX / 256, 256, 0, stream>>>(logits, depth, lab, nsq, probs, wbf, acc);
  k_gemm<<<BN * 6 * NSP, 256, 0, stream>>>(fbf, wbf, Pp, Qp);
  k_tail<<<NPIX / 256, 256, 0, stream>>>(probs, depth, inst, acc, s1, s2, cnt);
  k_pfinal<<<BN * CC, 256, 0, stream>>>(Pp, Qp, acc);
  k_final<<<1, 256, 0, stream>>>(s1, s2, cnt, acc, out);
}

// Round 9
// 194.694 us; speedup vs baseline: 1.8047x; 1.0850x over previous
//
#include <hip/hip_runtime.h>
#include <cstdint>
#include <cstddef>

#define BN 4
#define CC 27
#define HH 160
#define WW 160
#define HWp (HH*WW)        // 25600
#define NPIX (BN*HWp)      // 102400
#define DD 768
#define KK 24
#define NT 400             // 64-px tiles per image
#define NTS 20             // tiles (chunks) per gemm block: K = 1280 px
#define NSP 20             // splits: NT/NTS
#define NPH (NTS/2)        // 10 two-chunk phases
#define GEMMB (BN*6*NSP)   // 480 gemm blocks
#define TAILB (NPIX/256)   // 400 tail blocks

// ---- workspace float offsets ----
#define OFF_ACC 0                        // 32 scalars
#define OFF_S1 32                        // B*K*C = 2592
#define OFF_S2 (OFF_S1+2592)
#define OFF_CNT (OFF_S2+2592)            // 96
#define ZERO_N (OFF_CNT+96)              // 5312 floats zeroed each call
#define OFF_NSQ8 ZERO_N                  // 8*NPIX non-atomic partials (no zero needed)
#define OFF_LAB (OFF_NSQ8 + 8*NPIX)      // uint8 labels, NPIX bytes
#define OFF_PROBS (OFF_LAB + NPIX/4)     // bf16 probs: BN*CC*HWp ushorts
#define OFF_PP (OFF_PROBS + BN*CC*HWp/2) // NSP*BN*CC*DD fp32 partials (P)
#define OFF_QP (OFF_PP + NSP*BN*CC*DD)   // NSP*BN*CC*DD fp32 partials (Q)
#define OFF_FBF (OFF_QP + NSP*BN*CC*DD)  // fp8 feats TILED: (b,dt6,T)[128][64] swizzled
#define OFF_WBF (OFF_FBF + (size_t)BN*6*NT*8192/4)  // fp8 W TILED: (b,T)[64][64] swizzled

typedef __attribute__((ext_vector_type(4))) float f32x4;

__device__ __forceinline__ float wave_sum(float v) {
#pragma unroll
  for (int o = 32; o > 0; o >>= 1) v += __shfl_down(v, o, 64);
  return v;
}

__device__ __forceinline__ unsigned char f2fp8(float x) {
  return (unsigned char)(__builtin_amdgcn_cvt_pk_fp8_f32(x, x, 0, false) & 0xff);
}
__device__ __forceinline__ unsigned short f2bf(float x) {
  unsigned u = __builtin_bit_cast(unsigned, x);
  unsigned r = u + 0x7FFFu + ((u >> 16) & 1u);
  return (unsigned short)(r >> 16);
}
__device__ __forceinline__ float bf2f(unsigned short u) {
  unsigned v = ((unsigned)u) << 16;
  return __builtin_bit_cast(float, v);
}

__global__ void k_zero(float* __restrict__ w, int n) {
  int i = blockIdx.x * 256 + threadIdx.x;
  if (i < n) w[i] = 0.f;
}

// fused: [0,800) fp32 feats -> fp8 tiled/swizzled + nsq8 slab partials
//        [800,1200) depth-gradient mean + cause argmax labels
__global__ void __launch_bounds__(256) k_prefconv(const float* __restrict__ feats,
        const float* __restrict__ depth, const float* __restrict__ cl,
        unsigned char* __restrict__ fbf, float* __restrict__ nsq8,
        unsigned char* __restrict__ lab, float* __restrict__ acc) {
  int t = threadIdx.x;
  if (blockIdx.x < 800) {
    int fcid = blockIdx.x;
    int slab = fcid % 100;               // 100 slabs of 1024 px
    int y = fcid / 100;                  // 8-way d split
    int b = slab / (HWp / 1024);
    int px0 = (slab % (HWp / 1024)) * 1024;
    int d0 = y * (DD / 8);
    int p = px0 + 4 * t;
    int T = p >> 6, j = p & 63;
    const float* src = feats + ((size_t)b * DD + d0) * HWp + p;
    float n0 = 0.f, n1 = 0.f, n2 = 0.f, n3 = 0.f;
#pragma unroll 4
    for (int d = 0; d < DD / 8; ++d) {
      int dgl = d0 + d;
      float4 v = *(const float4*)(src + (size_t)d * HWp);
      n0 += v.x * v.x; n1 += v.y * v.y; n2 += v.z * v.z; n3 += v.w * v.w;
      int pk = __builtin_amdgcn_cvt_pk_fp8_f32(v.x, v.y, 0, false);
      pk = __builtin_amdgcn_cvt_pk_fp8_f32(v.z, v.w, pk, true);
      int dt = dgl >> 7, rin = dgl & 127;
      size_t addr = ((size_t)(b * 6 + dt) * NT + T) * 8192 + rin * 64
                  + (((j >> 3) ^ (rin & 7)) * 8) + (j & 7);
      *(int*)&fbf[addr] = pk;
    }
    float* nq = nsq8 + (size_t)y * NPIX + b * HWp + p;
    nq[0] = n0; nq[1] = n1; nq[2] = n2; nq[3] = n3;
  } else {
    int i = (blockIdx.x - 800) * 256 + t;
    float g = 0.f;
    {
      int b = i / HWp, r = i % HWp, h = r / WW, w = r % WW;
      const float* dp = depth + b * HWp;
      float d0 = dp[r];
      float gh = (h < HH-1) ? fabsf(dp[r+WW] - d0) : 0.f;
      float gw = (w < WW-1) ? fabsf(dp[r+1] - d0) : 0.f;
      g = gh + gw;
      const float* p = cl + (size_t)b * CC * HWp + r;
      float best = p[0]; int bi = 0;
#pragma unroll
      for (int c = 1; c < CC; ++c) {
        float v = p[(size_t)c * HWp];
        if (v > best) { best = v; bi = c; }
      }
      lab[i] = (unsigned char)bi;
    }
    __shared__ float red;
    if (t == 0) red = 0.f;
    __syncthreads();
    float s = wave_sum(g);
    if ((t & 63) == 0) atomicAdd(&red, s);
    __syncthreads();
    if (t == 0) atomicAdd(&acc[0], red);
  }
}

// per-pixel: softmax stats + distill/bpl/entropy scalars, bf16 probs,
// and fp8 W tiles (swizzled): row c = pt, row 32+c = pt*invnorm
__global__ void k_main(const float* __restrict__ logits, const float* __restrict__ depth,
                       const unsigned char* __restrict__ lab, const float* __restrict__ nsq8,
                       unsigned short* __restrict__ probs, unsigned char* __restrict__ wbf,
                       float* __restrict__ acc) {
  int i = blockIdx.x * 256 + threadIdx.x;
  float c_dist = 0.f, c_bnum = 0.f, c_bcnt = 0.f, c_ent = 0.f;
  {
    int b = i / HWp, r = i % HWp, h = r / WW, w = r % WW;
    const float* lg = logits + (size_t)b * CC * HWp + r;
    float x[CC];
    float m = -1e30f;
#pragma unroll
    for (int c = 0; c < CC; ++c) { x[c] = lg[(size_t)c * HWp]; m = fmaxf(m, x[c]); }
    float se = 0.f, sx = 0.f, set = 0.f;
#pragma unroll
    for (int c = 0; c < CC; ++c) {
      se += expf(x[c] - m);
      set += expf(10.f * (x[c] - m));
      sx += x[c];
    }
    float lse = logf(se);
    float inv_set = 1.f / set;
    float ns = 0.f;
#pragma unroll
    for (int y = 0; y < 8; ++y) ns += nsq8[(size_t)y * NPIX + i];
    float invn = 1.f / fmaxf(sqrtf(ns), 1e-12f);
    int l = lab[i];
    float xl = x[0];
    float ent = 0.f;
    unsigned short* pb = probs + (size_t)b * CC * HWp + r;
    int T = r >> 6, j = r & 63;
    unsigned char* wb = wbf + ((size_t)b * NT + T) * 4096;
#pragma unroll
    for (int c = 0; c < CC; ++c) {
      float lp = x[c] - m - lse;
      float p = expf(lp);
      pb[(size_t)c * HWp] = f2bf(p);
      float ptc = expf(10.f * (x[c] - m)) * inv_set;
      wb[c * 64 + (((j >> 3) ^ (c & 7)) * 8) + (j & 7)] = f2fp8(ptc);
      int c2 = 32 + c;
      wb[c2 * 64 + (((j >> 3) ^ (c2 & 7)) * 8) + (j & 7)] = f2fp8(ptc * invn);
      ent -= p * lp;
      if (c == l) xl = x[c];
    }
    float nll = m + lse - xl;
    float ce = 0.8f * nll + 0.2f * (m + lse - sx * (1.f / CC));
    float ptf = expf(-ce);
    float wgt = (1.f - ptf) * (1.f - ptf);
    if (l >= 11 && l <= 18) wgt *= 2.f;
    const float* dp = depth + b * HWp;
    float d0 = dp[r];
    float gh = (h < HH-1) ? fabsf(dp[r+WW] - d0) : 0.f;
    float gw = (w < WW-1) ? fabsf(dp[r+1] - d0) : 0.f;
    float gmean = acc[0] * (1.f / NPIX);
    float gnorm = (gh + gw) / (gmean + 1e-6f);
    wgt *= 1.f + 0.1f * fminf(gnorm, 3.f);
    const unsigned char* lb = lab + b * HWp;
    int lL = lb[h*WW + (w>0 ? w-1 : w)];
    int lR = lb[h*WW + (w<WW-1 ? w+1 : w)];
    int lU = lb[(h>0 ? h-1 : h)*WW + w];
    int lD = lb[(h<HH-1 ? h+1 : h)*WW + w];
    float bnd = ((l != lL) | (l != lR) | (l != lU) | (l != lD)) ? 1.f : 0.f;
    c_dist = ce * wgt;
    c_bnum = ce * bnd;
    c_bcnt = bnd;
    c_ent = ent;
  }
  __shared__ float red[4];
  if (threadIdx.x < 4) red[threadIdx.x] = 0.f;
  __syncthreads();
  c_dist = wave_sum(c_dist); c_bnum = wave_sum(c_bnum);
  c_bcnt = wave_sum(c_bcnt); c_ent = wave_sum(c_ent);
  if ((threadIdx.x & 63) == 0) {
    atomicAdd(&red[0], c_dist); atomicAdd(&red[1], c_bnum);
    atomicAdd(&red[2], c_bcnt); atomicAdd(&red[3], c_ent);
  }
  __syncthreads();
  if (threadIdx.x == 0) {
    atomicAdd(&acc[1], red[0]); atomicAdd(&acc[2], red[1]);
    atomicAdd(&acc[3], red[2]); atomicAdd(&acc[4], red[3]);
  }
}

// fused co-scheduled kernel:
//   blocks [0,480): fp8 MFMA GEMM (as r8), 72KB LDS, atomic-free partial epilogue
//   blocks [480,880): tail (align + instance BCE + instance-uniformity histogram)
__global__ void __launch_bounds__(256) k_gemmtail(const unsigned char* __restrict__ fbf,
        const unsigned char* __restrict__ wbf,
        float* __restrict__ Pp, float* __restrict__ Qp,
        const unsigned short* __restrict__ probs, const float* __restrict__ depth,
        const int* __restrict__ inst, float* __restrict__ acc,
        float* __restrict__ s1g, float* __restrict__ s2g, float* __restrict__ cntg) {
  __shared__ __align__(16) unsigned char smem[73728];
  int t = threadIdx.x;
  if (blockIdx.x < GEMMB) {
    unsigned char (*As)[2][8192] = (unsigned char (*)[2][8192])smem;
    unsigned char (*Ws)[2][4096] = (unsigned char (*)[2][4096])(smem + 49152);
    int orig = blockIdx.x;
    int bx = (orig & 7) * 60 + (orig >> 3);   // bijective: 480 = 8*60
    int s  = bx % NSP;
    int dt = (bx / NSP) % 6;
    int b  = bx / (NSP * 6);
    int wave = t >> 6, lane = t & 63;
    int g = lane >> 4, rr = lane & 15;
    f32x4 acc4[2][4] = {};
    const unsigned char* Abase = fbf + ((size_t)(b*6+dt)*NT + s*NTS) * 8192;
    const unsigned char* Wbase = wbf + ((size_t)b*NT + s*NTS) * 4096;

#define STAGE2(ph, bufi) do { \
    _Pragma("unroll") \
    for (int c2_ = 0; c2_ < 2; ++c2_) { \
      const unsigned char* as_ = Abase + (size_t)((ph)*2 + c2_) * 8192; \
      const unsigned char* ws_ = Wbase + (size_t)((ph)*2 + c2_) * 4096; \
      _Pragma("unroll") \
      for (int i_ = 0; i_ < 2; ++i_) { \
        int off_ = wave*2048 + i_*1024; \
        __builtin_amdgcn_global_load_lds( \
          (const __attribute__((address_space(1))) void*)(as_ + off_ + lane*16), \
          (__attribute__((address_space(3))) void*)&As[bufi][c2_][off_], 16, 0, 0); \
      } \
      { \
        int off_ = wave*1024; \
        __builtin_amdgcn_global_load_lds( \
          (const __attribute__((address_space(1))) void*)(ws_ + off_ + lane*16), \
          (__attribute__((address_space(3))) void*)&Ws[bufi][c2_][off_], 16, 0, 0); \
      } \
    } \
  } while (0)

    STAGE2(0, 0);
    STAGE2(1, 1);
    int cur = 0;
    for (int ph = 0; ph < NPH; ++ph) {
      if (ph + 2 < NPH) {
        STAGE2(ph + 2, (cur + 2) % 3);
        asm volatile("s_waitcnt vmcnt(12)" ::: "memory");
      } else if (ph + 1 < NPH) {
        asm volatile("s_waitcnt vmcnt(6)" ::: "memory");
      } else {
        asm volatile("s_waitcnt vmcnt(0)" ::: "memory");
      }
      __builtin_amdgcn_s_barrier();
      __builtin_amdgcn_sched_barrier(0);
#pragma unroll
      for (int c2 = 0; c2 < 2; ++c2) {
#pragma unroll
        for (int ks = 0; ks < 2; ++ks) {
          long a[2]; long wf[4];
#pragma unroll
          for (int dd = 0; dd < 2; ++dd) {
            int row = (wave*2 + dd)*16 + rr;
            int ck = (ks*4 + g) ^ (row & 7);
            a[dd] = *(const long*)&As[cur][c2][row*64 + ck*8];
          }
#pragma unroll
          for (int ct = 0; ct < 4; ++ct) {
            int row = ct*16 + rr;
            int ck = (ks*4 + g) ^ (row & 7);
            wf[ct] = *(const long*)&Ws[cur][c2][row*64 + ck*8];
          }
#pragma unroll
          for (int dd = 0; dd < 2; ++dd)
#pragma unroll
            for (int ct = 0; ct < 4; ++ct)
              acc4[dd][ct] = __builtin_amdgcn_mfma_f32_16x16x32_fp8_fp8(a[dd], wf[ct], acc4[dd][ct], 0, 0, 0);
        }
      }
      __builtin_amdgcn_sched_barrier(0);
      __builtin_amdgcn_s_barrier();
      cur = (cur + 1) % 3;
    }
#undef STAGE2
#pragma unroll
    for (int dd = 0; dd < 2; ++dd) {
#pragma unroll
      for (int ct = 0; ct < 4; ++ct) {
        int cp = ct * 16 + rr;
        int d = dt * 128 + (wave * 2 + dd) * 16 + g * 4;
        f32x4 v = acc4[dd][ct];
        if (cp < CC)
          *(f32x4*)&Pp[(((size_t)s * BN + b) * CC + cp) * DD + d] = v;
        else if (cp >= 32 && cp < 32 + CC)
          *(f32x4*)&Qp[(((size_t)s * BN + b) * CC + (cp - 32)) * DD + d] = v;
      }
    }
  } else {
    float* ls1 = (float*)smem;                 // [4][KK*CC]
    float* ls2 = ls1 + 4*KK*CC;                // [4][KK*CC]
    float* lc  = ls2 + 4*KK*CC;                // [4][KK]
    float* red = lc + 4*KK;                    // [4]
    int wv = t >> 6;
    for (int idx = t; idx < 4*KK*CC; idx += 256) { ls1[idx] = 0.f; ls2[idx] = 0.f; }
    if (t < 4*KK) lc[t] = 0.f;
    if (t < 4) red[t] = 0.f;
    __syncthreads();
    int i = (blockIdx.x - GEMMB) * 256 + t;
    int b = i / HWp, r = i % HWp, h = r / WW, w = r % WW;
    const unsigned short* P = probs + (size_t)b * CC * HWp + r;
    const int* ip = inst + b * HWp;
    int id = ip[r];
    atomicAdd(&lc[wv*KK + id], 1.f);
    bool hasR = (w < WW-1), hasD = (h < HH-1);
    float sh = 0.f, sv = 0.f, mh = 0.f, mw = 0.f;
#pragma unroll
    for (int c = 0; c < CC; ++c) {
      float p  = bf2f(P[(size_t)c * HWp]);
      atomicAdd(&ls1[(wv*KK + id)*CC + c], p);
      atomicAdd(&ls2[(wv*KK + id)*CC + c], p * p);
      float pr = hasR ? bf2f(P[(size_t)c * HWp + 1])  : p;
      float pd = hasD ? bf2f(P[(size_t)c * HWp + WW]) : p;
      float dr = pr - p, dd = pd - p;
      sh += dr * dr; sv += dd * dd;
      mw = fmaxf(mw, fabsf(dr)); mh = fmaxf(mh, fabsf(dd));
    }
    float aH = 0.f, aV = 0.f, bh = 0.f, bw = 0.f;
    const float* dp = depth + b * HWp;
    float d0 = dp[r];
    if (hasR) {
      float ddh = dp[r+1] - d0;
      aH = expf(-(ddh*ddh) * 200.f) * sh;
      float y = (ip[r+1] != ip[r]) ? 1.f : 0.f;
      float xx = fminf(fmaxf(mw, 1e-6f), 1.f - 1e-6f);
      bw = -(y * logf(xx) + (1.f - y) * log1pf(-xx));
    }
    if (hasD) {
      float ddv = dp[r+WW] - d0;
      aV = expf(-(ddv*ddv) * 200.f) * sv;
      float y = (ip[r+WW] != ip[r]) ? 1.f : 0.f;
      float xx = fminf(fmaxf(mh, 1e-6f), 1.f - 1e-6f);
      bh = -(y * logf(xx) + (1.f - y) * log1pf(-xx));
    }
    __syncthreads();   // ensure red[] init visible (done above)
    aH = wave_sum(aH); aV = wave_sum(aV); bh = wave_sum(bh); bw = wave_sum(bw);
    if ((t & 63) == 0) {
      atomicAdd(&red[0], aH); atomicAdd(&red[1], aV);
      atomicAdd(&red[2], bh); atomicAdd(&red[3], bw);
    }
    __syncthreads();
    if (t == 0) {
      atomicAdd(&acc[5], red[0]); atomicAdd(&acc[6], red[1]);
      atomicAdd(&acc[7], red[2]); atomicAdd(&acc[8], red[3]);
    }
    for (int idx = t; idx < KK*CC; idx += 256) {
      atomicAdd(&s1g[b*KK*CC + idx], ls1[idx]+ls1[KK*CC+idx]+ls1[2*KK*CC+idx]+ls1[3*KK*CC+idx]);
      atomicAdd(&s2g[b*KK*CC + idx], ls2[idx]+ls2[KK*CC+idx]+ls2[2*KK*CC+idx]+ls2[3*KK*CC+idx]);
    }
    if (t < KK) atomicAdd(&cntg[b*KK + t], lc[t]+lc[KK+t]+lc[2*KK+t]+lc[3*KK+t]);
  }
}

__global__ void k_pfinal(const float* __restrict__ Pp, const float* __restrict__ Qp,
                         float* __restrict__ acc) {
  int bc = blockIdx.x;   // b*CC + c
  int b = bc / CC, c = bc % CC;
  float dot = 0.f, nsq = 0.f;
  for (int d = threadIdx.x; d < DD; d += 256) {
    float p = 0.f, q = 0.f;
#pragma unroll
    for (int s = 0; s < NSP; ++s) {
      size_t off = (((size_t)s * BN + b) * CC + c) * DD + d;
      p += Pp[off]; q += Qp[off];
    }
    dot += p * q; nsq += p * p;
  }
  __shared__ float red[2];
  if (threadIdx.x < 2) red[threadIdx.x] = 0.f;
  __syncthreads();
  dot = wave_sum(dot); nsq = wave_sum(nsq);
  if ((threadIdx.x & 63) == 0) { atomicAdd(&red[0], dot); atomicAdd(&red[1], nsq); }
  __syncthreads();
  if (threadIdx.x == 0) atomicAdd(&acc[9], red[0] / fmaxf(sqrtf(red[1]), 1e-12f));
}

__global__ void k_final(const float* __restrict__ s1g, const float* __restrict__ s2g,
                        const float* __restrict__ cntg, const float* __restrict__ acc,
                        float* __restrict__ out) {
  int t = threadIdx.x;
  float vsum = 0.f, vcnt = 0.f;
  if (t < BN*KK) {
    int k = t % KK;
    float count = cntg[t];
    float nc = fmaxf(count, 1.f);
    float var = 0.f;
#pragma unroll
    for (int c = 0; c < CC; ++c) {
      float m1 = s1g[t*CC + c] / nc;
      var += s2g[t*CC + c] / nc - m1 * m1;
    }
    var *= (1.f / CC);
    if (k > 0 && count >= 25.f) { vsum = var; vcnt = 1.f; }
  }
  __shared__ float red[2];
  if (t < 2) red[t] = 0.f;
  __syncthreads();
  vsum = wave_sum(vsum); vcnt = wave_sum(vcnt);
  if ((t & 63) == 0) { atomicAdd(&red[0], vsum); atomicAdd(&red[1], vcnt); }
  __syncthreads();
  if (t == 0) {
    float l_distill = acc[1] * (1.f / NPIX);
    float bcnt = acc[3];
    float l_bpl = (bcnt > 0.f) ? acc[2] / fmaxf(bcnt, 1.f) : 0.f;
    float l_align = acc[5] * (1.f / (BN*HH*(WW-1))) + acc[6] * (1.f / (BN*(HH-1)*WW));
    float l_ent = acc[4] * (1.f / NPIX);
    float l_ib = 0.5f * (acc[7] * (1.f / (BN*(HH-1)*WW)) + acc[8] * (1.f / (BN*HH*(WW-1))));
    float l_proto = -acc[9] * (1.f / NPIX);
    float l_iu = red[0] / fmaxf(red[1], 1.f);
    out[0] = 1.0f*l_distill + 0.5f*l_bpl + 5.0f*l_align + 0.5f*l_proto +
             0.3f*l_ent + 0.5f*l_iu + 0.5f*l_ib;
  }
}

extern "C" void kernel_launch(void* const* d_in, const int* in_sizes, int n_in,
                              void* d_out, int out_size, void* d_ws, size_t ws_size,
                              hipStream_t stream) {
  (void)in_sizes; (void)n_in; (void)out_size; (void)ws_size;
  const float* logits = (const float*)d_in[0];
  const float* cause  = (const float*)d_in[1];
  const float* feats  = (const float*)d_in[2];
  const float* depth  = (const float*)d_in[3];
  const int*   inst   = (const int*)d_in[4];
  float* ws = (float*)d_ws;
  float* acc = ws + OFF_ACC;
  float* s1  = ws + OFF_S1;
  float* s2  = ws + OFF_S2;
  float* cnt = ws + OFF_CNT;
  float* nsq8 = ws + OFF_NSQ8;
  float* Pp  = ws + OFF_PP;
  float* Qp  = ws + OFF_QP;
  unsigned char* lab = (unsigned char*)(ws + OFF_LAB);
  unsigned short* probs = (unsigned short*)(ws + OFF_PROBS);
  unsigned char* fbf = (unsigned char*)(ws + OFF_FBF);
  unsigned char* wbf = (unsigned char*)(ws + OFF_WBF);
  float* out = (float*)d_out;

  k_zero<<<(ZERO_N + 255) / 256, 256, 0, stream>>>(ws, ZERO_N);
  k_prefconv<<<1200, 256, 0, stream>>>(feats, depth, cause, fbf, nsq8, lab, acc);
  k_main<<<NPIX / 256, 256, 0, stream>>>(logits, depth, lab, nsq8, probs, wbf, acc);
  k_gemmtail<<<GEMMB + TAILB, 256, 0, stream>>>(fbf, wbf, Pp, Qp, probs, depth, inst,
                                                acc, s1, s2, cnt);
  k_pfinal<<<BN * CC, 256, 0, stream>>>(Pp, Qp, acc);
  k_final<<<1, 256, 0, stream>>>(s1, s2, cnt, acc, out);
}

// Round 10
// 191.098 us; speedup vs baseline: 1.8387x; 1.0188x over previous
//
#include <hip/hip_runtime.h>
#include <cstdint>
#include <cstddef>

#define BN 4
#define CC 27
#define HH 160
#define WW 160
#define HWp (HH*WW)        // 25600
#define NPIX (BN*HWp)      // 102400
#define DD 768
#define KK 24
#define NT 400             // 64-px tiles per image
#define NTS 20             // tiles per gemm block: K = 1280 px
#define NSP 20             // splits: NT/NTS
#define NPH (NTS/2)        // 10 two-chunk phases
#define GEMMB (BN*6*NSP)   // 480 gemm blocks
#define TAILB (NPIX/256)   // 400 tail blocks

// ---- workspace float offsets ----
#define OFF_ACC 0                        // 32 scalars
#define OFF_S1 32                        // B*K*C = 2592
#define OFF_S2 (OFF_S1+2592)
#define OFF_CNT (OFF_S2+2592)            // 96
#define ZERO_N (OFF_CNT+96)              // 5312 floats zeroed each call
#define OFF_NSQ8 ZERO_N                  // 8*NPIX partials (no zero needed)
#define OFF_LAB (OFF_NSQ8 + 8*NPIX)      // uint8 labels, NPIX bytes
#define OFF_CE (OFF_LAB + NPIX/4)        // NPIX fp32 per-pixel CE
#define OFF_PROBS (OFF_CE + NPIX)        // bf16 probs: BN*CC*HWp ushorts
#define OFF_PP (OFF_PROBS + BN*CC*HWp/2) // NSP*BN*CC*DD fp32 partials (P)
#define OFF_QP (OFF_PP + NSP*BN*CC*DD)
#define OFF_FBF (OFF_QP + NSP*BN*CC*DD)  // fp8 feats TILED (b,dt6,T)[128][64] swizzled
#define OFF_WBF (OFF_FBF + (size_t)BN*6*NT*8192/4)  // fp8 W TILED (b,T)[64][64] swizzled

typedef __attribute__((ext_vector_type(4))) float f32x4;

__device__ __forceinline__ float wave_sum(float v) {
#pragma unroll
  for (int o = 32; o > 0; o >>= 1) v += __shfl_down(v, o, 64);
  return v;
}

__device__ __forceinline__ unsigned char f2fp8(float x) {
  return (unsigned char)(__builtin_amdgcn_cvt_pk_fp8_f32(x, x, 0, false) & 0xff);
}
__device__ __forceinline__ unsigned short f2bf(float x) {
  unsigned u = __builtin_bit_cast(unsigned, x);
  unsigned r = u + 0x7FFFu + ((u >> 16) & 1u);
  return (unsigned short)(r >> 16);
}
__device__ __forceinline__ float bf2f(unsigned short u) {
  unsigned v = ((unsigned)u) << 16;
  return __builtin_bit_cast(float, v);
}

__global__ void k_zero(float* __restrict__ w, int n) {
  int i = blockIdx.x * 256 + threadIdx.x;
  if (i < n) w[i] = 0.f;
}

// k_big: [0,400) fconv: fp32 feats -> fp8 tiled/swizzled (8 px/thread, 8B stores)
//                      + nsq8 slab partials
//        [400,800) mainA: cause argmax + softmax + probs(bf16) + W-pt rows(fp8)
//                      + per-px ce + ent + depth-grad mean  (independent of feats)
__global__ void __launch_bounds__(256) k_big(const float* __restrict__ feats,
        const float* __restrict__ logits, const float* __restrict__ cause,
        const float* __restrict__ depth,
        unsigned char* __restrict__ fbf, float* __restrict__ nsq8,
        unsigned char* __restrict__ lab, float* __restrict__ ce_arr,
        unsigned short* __restrict__ probs, unsigned char* __restrict__ wbf,
        float* __restrict__ acc) {
  int t = threadIdx.x;
  if (blockIdx.x < 400) {
    int fcid = blockIdx.x;
    int slab = fcid % 50;                // 50 slabs of 2048 px (global)
    int y = fcid / 50;                   // 8-way d split, 96 rows each
    int i = slab * 2048 + 8 * t;
    int b = i / HWp, r = i % HWp;
    int T = r >> 6, chunk = (r & 63) >> 3;
    const float* src0 = feats + ((size_t)b * DD + y * 96) * HWp + r;
    float n[8] = {0,0,0,0,0,0,0,0};
#pragma unroll 4
    for (int d = 0; d < 96; ++d) {
      int dgl = y * 96 + d;
      const float* src = src0 + (size_t)d * HWp;
      float4 v0 = *(const float4*)src;
      float4 v1 = *(const float4*)(src + 4);
      n[0]+=v0.x*v0.x; n[1]+=v0.y*v0.y; n[2]+=v0.z*v0.z; n[3]+=v0.w*v0.w;
      n[4]+=v1.x*v1.x; n[5]+=v1.y*v1.y; n[6]+=v1.z*v1.z; n[7]+=v1.w*v1.w;
      int pk0 = __builtin_amdgcn_cvt_pk_fp8_f32(v0.x, v0.y, 0, false);
      pk0 = __builtin_amdgcn_cvt_pk_fp8_f32(v0.z, v0.w, pk0, true);
      int pk1 = __builtin_amdgcn_cvt_pk_fp8_f32(v1.x, v1.y, 0, false);
      pk1 = __builtin_amdgcn_cvt_pk_fp8_f32(v1.z, v1.w, pk1, true);
      int dt = dgl >> 7, rin = dgl & 127;
      size_t addr = ((size_t)(b * 6 + dt) * NT + T) * 8192 + rin * 64
                  + ((chunk ^ (rin & 7)) * 8);
      int2 pk = make_int2(pk0, pk1);
      *(int2*)&fbf[addr] = pk;
    }
    float* nq = nsq8 + (size_t)y * NPIX + i;
    *(float4*)nq = make_float4(n[0], n[1], n[2], n[3]);
    *(float4*)(nq + 4) = make_float4(n[4], n[5], n[6], n[7]);
  } else {
    int i = (blockIdx.x - 400) * 256 + t;
    int b = i / HWp, r = i % HWp, h = r / WW, w = r % WW;
    float x[CC];
    // cause argmax
    {
      const float* cp = cause + (size_t)b * CC * HWp + r;
      float best = -1e30f; int bi = 0;
#pragma unroll
      for (int c = 0; c < CC; ++c) {
        float v = cp[(size_t)c * HWp];
        if (v > best) { best = v; bi = c; }
      }
      lab[i] = (unsigned char)bi;
      // softmax over logits
      const float* lg = logits + (size_t)b * CC * HWp + r;
      float m = -1e30f;
#pragma unroll
      for (int c = 0; c < CC; ++c) { x[c] = lg[(size_t)c * HWp]; m = fmaxf(m, x[c]); }
      float sx = 0.f, xl = 0.f;
#pragma unroll
      for (int c = 0; c < CC; ++c) { sx += x[c]; if (c == bi) xl = x[c]; }
      float se = 0.f, set = 0.f, u = 0.f;
#pragma unroll
      for (int c = 0; c < CC; ++c) {
        float tc = x[c] - m;
        float e = expf(tc);
        se += e; u += e * tc;
        float e2 = e * e, e4 = e2 * e2;
        set += e4 * e4 * e2;
        x[c] = e;
      }
      float lse = logf(se);
      float inv_se = 1.f / se, inv_set = 1.f / set;
      float ent = lse - u * inv_se;
      unsigned short* pb = probs + (size_t)b * CC * HWp + r;
      int T = r >> 6, j = r & 63;
      unsigned char* wb = wbf + ((size_t)b * NT + T) * 4096;
#pragma unroll
      for (int c = 0; c < CC; ++c) {
        float e = x[c];
        pb[(size_t)c * HWp] = f2bf(e * inv_se);
        float e2 = e * e, e4 = e2 * e2;
        float ptc = (e4 * e4 * e2) * inv_set;
        wb[c * 64 + (((j >> 3) ^ (c & 7)) * 8) + (j & 7)] = f2fp8(ptc);
      }
      float ce = 0.8f * (m + lse - xl) + 0.2f * (m + lse - sx * (1.f / CC));
      ce_arr[i] = ce;
      // depth gradient (for global mean)
      const float* dp = depth + b * HWp;
      float d0 = dp[r];
      float gh = (h < HH-1) ? fabsf(dp[r+WW] - d0) : 0.f;
      float gw = (w < WW-1) ? fabsf(dp[r+1] - d0) : 0.f;
      float g = gh + gw;
      __shared__ float red[2];
      if (t < 2) red[t] = 0.f;
      __syncthreads();
      g = wave_sum(g); float es = wave_sum(ent);
      if ((t & 63) == 0) { atomicAdd(&red[0], g); atomicAdd(&red[1], es); }
      __syncthreads();
      if (t == 0) { atomicAdd(&acc[0], red[0]); atomicAdd(&acc[4], red[1]); }
    }
  }
}

// mainB: W rows 32+c = fp8( fp8dec(pt) * invnorm ). 400 blocks x 4 tiles.
__global__ void __launch_bounds__(256) k_mainB(const float* __restrict__ nsq8,
        unsigned char* __restrict__ wbf) {
  int t = threadIdx.x;
  int tt = blockIdx.x * 4 + (t >> 6);    // global tile in [0, BN*NT)
  int j = t & 63;
  int b = tt / NT, T = tt % NT;
  int i = b * HWp + T * 64 + j;
  float ns = 0.f;
#pragma unroll
  for (int y = 0; y < 8; ++y) ns += nsq8[(size_t)y * NPIX + i];
  float invn = 1.f / fmaxf(sqrtf(ns), 1e-12f);
  unsigned char* wb = wbf + ((size_t)b * NT + T) * 4096;
  int base = (((j >> 3)) * 8) + (j & 7);
#pragma unroll
  for (int c = 0; c < CC; ++c) {
    int a1 = c * 64 + ((((j >> 3) ^ (c & 7))) * 8) + (j & 7);
    float f = __builtin_amdgcn_cvt_f32_fp8((int)wb[a1], 0);
    wb[a1 + 32 * 64] = f2fp8(f * invn);
  }
  (void)base;
}

// fused co-scheduled kernel:
//   blocks [0,480): fp8 MFMA GEMM, 72KB LDS, atomic-free partial epilogue
//   blocks [480,880): tail (distill + bpl + align + instance BCE + iu histogram)
__global__ void __launch_bounds__(256) k_gemmtail(const unsigned char* __restrict__ fbf,
        const unsigned char* __restrict__ wbf,
        float* __restrict__ Pp, float* __restrict__ Qp,
        const unsigned short* __restrict__ probs, const float* __restrict__ depth,
        const int* __restrict__ inst, const unsigned char* __restrict__ lab,
        const float* __restrict__ ce_arr, float* __restrict__ acc,
        float* __restrict__ s1g, float* __restrict__ s2g, float* __restrict__ cntg) {
  __shared__ __align__(16) unsigned char smem[73728];
  int t = threadIdx.x;
  if (blockIdx.x < GEMMB) {
    unsigned char (*As)[2][8192] = (unsigned char (*)[2][8192])smem;
    unsigned char (*Ws)[2][4096] = (unsigned char (*)[2][4096])(smem + 49152);
    int orig = blockIdx.x;
    int bx = (orig & 7) * 60 + (orig >> 3);   // bijective: 480 = 8*60
    int s  = bx % NSP;
    int dt = (bx / NSP) % 6;
    int b  = bx / (NSP * 6);
    int wave = t >> 6, lane = t & 63;
    int g = lane >> 4, rr = lane & 15;
    f32x4 acc4[2][4] = {};
    const unsigned char* Abase = fbf + ((size_t)(b*6+dt)*NT + s*NTS) * 8192;
    const unsigned char* Wbase = wbf + ((size_t)b*NT + s*NTS) * 4096;

#define STAGE2(ph, bufi) do { \
    _Pragma("unroll") \
    for (int c2_ = 0; c2_ < 2; ++c2_) { \
      const unsigned char* as_ = Abase + (size_t)((ph)*2 + c2_) * 8192; \
      const unsigned char* ws_ = Wbase + (size_t)((ph)*2 + c2_) * 4096; \
      _Pragma("unroll") \
      for (int i_ = 0; i_ < 2; ++i_) { \
        int off_ = wave*2048 + i_*1024; \
        __builtin_amdgcn_global_load_lds( \
          (const __attribute__((address_space(1))) void*)(as_ + off_ + lane*16), \
          (__attribute__((address_space(3))) void*)&As[bufi][c2_][off_], 16, 0, 0); \
      } \
      { \
        int off_ = wave*1024; \
        __builtin_amdgcn_global_load_lds( \
          (const __attribute__((address_space(1))) void*)(ws_ + off_ + lane*16), \
          (__attribute__((address_space(3))) void*)&Ws[bufi][c2_][off_], 16, 0, 0); \
      } \
    } \
  } while (0)

    STAGE2(0, 0);
    STAGE2(1, 1);
    int cur = 0;
    for (int ph = 0; ph < NPH; ++ph) {
      if (ph + 2 < NPH) {
        STAGE2(ph + 2, (cur + 2) % 3);
        asm volatile("s_waitcnt vmcnt(12)" ::: "memory");
      } else if (ph + 1 < NPH) {
        asm volatile("s_waitcnt vmcnt(6)" ::: "memory");
      } else {
        asm volatile("s_waitcnt vmcnt(0)" ::: "memory");
      }
      __builtin_amdgcn_s_barrier();
      __builtin_amdgcn_sched_barrier(0);
#pragma unroll
      for (int c2 = 0; c2 < 2; ++c2) {
#pragma unroll
        for (int ks = 0; ks < 2; ++ks) {
          long a[2]; long wf[4];
#pragma unroll
          for (int dd = 0; dd < 2; ++dd) {
            int row = (wave*2 + dd)*16 + rr;
            int ck = (ks*4 + g) ^ (row & 7);
            a[dd] = *(const long*)&As[cur][c2][row*64 + ck*8];
          }
#pragma unroll
          for (int ct = 0; ct < 4; ++ct) {
            int row = ct*16 + rr;
            int ck = (ks*4 + g) ^ (row & 7);
            wf[ct] = *(const long*)&Ws[cur][c2][row*64 + ck*8];
          }
#pragma unroll
          for (int dd = 0; dd < 2; ++dd)
#pragma unroll
            for (int ct = 0; ct < 4; ++ct)
              acc4[dd][ct] = __builtin_amdgcn_mfma_f32_16x16x32_fp8_fp8(a[dd], wf[ct], acc4[dd][ct], 0, 0, 0);
        }
      }
      __builtin_amdgcn_sched_barrier(0);
      __builtin_amdgcn_s_barrier();
      cur = (cur + 1) % 3;
    }
#undef STAGE2
#pragma unroll
    for (int dd = 0; dd < 2; ++dd) {
#pragma unroll
      for (int ct = 0; ct < 4; ++ct) {
        int cp = ct * 16 + rr;
        int d = dt * 128 + (wave * 2 + dd) * 16 + g * 4;
        f32x4 v = acc4[dd][ct];
        if (cp < CC)
          *(f32x4*)&Pp[(((size_t)s * BN + b) * CC + cp) * DD + d] = v;
        else if (cp >= 32 && cp < 32 + CC)
          *(f32x4*)&Qp[(((size_t)s * BN + b) * CC + (cp - 32)) * DD + d] = v;
      }
    }
  } else {
    float* ls1 = (float*)smem;                 // [4][KK*CC]
    float* ls2 = ls1 + 4*KK*CC;
    float* lc  = ls2 + 4*KK*CC;                // [4][KK]
    float* red = lc + 4*KK;                    // [7]
    int wv = t >> 6;
    for (int idx = t; idx < 4*KK*CC; idx += 256) { ls1[idx] = 0.f; ls2[idx] = 0.f; }
    if (t < 4*KK) lc[t] = 0.f;
    if (t < 7) red[t] = 0.f;
    __syncthreads();
    int i = (blockIdx.x - GEMMB) * 256 + t;
    int b = i / HWp, r = i % HWp, h = r / WW, w = r % WW;
    const unsigned short* P = probs + (size_t)b * CC * HWp + r;
    const int* ip = inst + b * HWp;
    int id = ip[r];
    atomicAdd(&lc[wv*KK + id], 1.f);
    bool hasR = (w < WW-1), hasD = (h < HH-1);
    float sh = 0.f, sv = 0.f, mh = 0.f, mw = 0.f;
#pragma unroll
    for (int c = 0; c < CC; ++c) {
      float p  = bf2f(P[(size_t)c * HWp]);
      atomicAdd(&ls1[(wv*KK + id)*CC + c], p);
      atomicAdd(&ls2[(wv*KK + id)*CC + c], p * p);
      float pr = hasR ? bf2f(P[(size_t)c * HWp + 1])  : p;
      float pd = hasD ? bf2f(P[(size_t)c * HWp + WW]) : p;
      float dr = pr - p, dd = pd - p;
      sh += dr * dr; sv += dd * dd;
      mw = fmaxf(mw, fabsf(dr)); mh = fmaxf(mh, fabsf(dd));
    }
    const float* dp = depth + b * HWp;
    float d0 = dp[r];
    float aH = 0.f, aV = 0.f, bh = 0.f, bw = 0.f;
    float gh = 0.f, gw = 0.f;
    if (hasR) {
      float ddh = dp[r+1] - d0;
      gw = fabsf(ddh);
      aH = expf(-(ddh*ddh) * 200.f) * sh;
      float y = (ip[r+1] != ip[r]) ? 1.f : 0.f;
      float xx = fminf(fmaxf(mw, 1e-6f), 1.f - 1e-6f);
      bw = -(y * logf(xx) + (1.f - y) * log1pf(-xx));
    }
    if (hasD) {
      float ddv = dp[r+WW] - d0;
      gh = fabsf(ddv);
      aV = expf(-(ddv*ddv) * 200.f) * sv;
      float y = (ip[r+WW] != ip[r]) ? 1.f : 0.f;
      float xx = fminf(fmaxf(mh, 1e-6f), 1.f - 1e-6f);
      bh = -(y * logf(xx) + (1.f - y) * log1pf(-xx));
    }
    // distill + bpl from stored ce
    float ce = ce_arr[i];
    int l = lab[i];
    float ptf = expf(-ce);
    float wgt = (1.f - ptf) * (1.f - ptf);
    if (l >= 11 && l <= 18) wgt *= 2.f;
    float gmean = acc[0] * (1.f / NPIX);
    float gnorm = (gh + gw) / (gmean + 1e-6f);
    wgt *= 1.f + 0.1f * fminf(gnorm, 3.f);
    const unsigned char* lb = lab + b * HWp;
    int lL = lb[h*WW + (w>0 ? w-1 : w)];
    int lR = lb[h*WW + (w<WW-1 ? w+1 : w)];
    int lU = lb[(h>0 ? h-1 : h)*WW + w];
    int lD = lb[(h<HH-1 ? h+1 : h)*WW + w];
    float bnd = ((l != lL) | (l != lR) | (l != lU) | (l != lD)) ? 1.f : 0.f;
    float c_dist = ce * wgt, c_bnum = ce * bnd, c_bcnt = bnd;
    __syncthreads();
    aH = wave_sum(aH); aV = wave_sum(aV); bh = wave_sum(bh); bw = wave_sum(bw);
    c_dist = wave_sum(c_dist); c_bnum = wave_sum(c_bnum); c_bcnt = wave_sum(c_bcnt);
    if ((t & 63) == 0) {
      atomicAdd(&red[0], aH); atomicAdd(&red[1], aV);
      atomicAdd(&red[2], bh); atomicAdd(&red[3], bw);
      atomicAdd(&red[4], c_dist); atomicAdd(&red[5], c_bnum); atomicAdd(&red[6], c_bcnt);
    }
    __syncthreads();
    if (t == 0) {
      atomicAdd(&acc[5], red[0]); atomicAdd(&acc[6], red[1]);
      atomicAdd(&acc[7], red[2]); atomicAdd(&acc[8], red[3]);
      atomicAdd(&acc[1], red[4]); atomicAdd(&acc[2], red[5]); atomicAdd(&acc[3], red[6]);
    }
    for (int idx = t; idx < KK*CC; idx += 256) {
      atomicAdd(&s1g[b*KK*CC + idx], ls1[idx]+ls1[KK*CC+idx]+ls1[2*KK*CC+idx]+ls1[3*KK*CC+idx]);
      atomicAdd(&s2g[b*KK*CC + idx], ls2[idx]+ls2[KK*CC+idx]+ls2[2*KK*CC+idx]+ls2[3*KK*CC+idx]);
    }
    if (t < KK) atomicAdd(&cntg[b*KK + t], lc[t]+lc[KK+t]+lc[2*KK+t]+lc[3*KK+t]);
  }
}

__global__ void k_pfinal(const float* __restrict__ Pp, const float* __restrict__ Qp,
                         float* __restrict__ acc) {
  int bc = blockIdx.x;   // b*CC + c
  int b = bc / CC, c = bc % CC;
  float dot = 0.f, nsq = 0.f;
  for (int d = threadIdx.x; d < DD; d += 256) {
    float p = 0.f, q = 0.f;
#pragma unroll
    for (int s = 0; s < NSP; ++s) {
      size_t off = (((size_t)s * BN + b) * CC + c) * DD + d;
      p += Pp[off]; q += Qp[off];
    }
    dot += p * q; nsq += p * p;
  }
  __shared__ float red[2];
  if (threadIdx.x < 2) red[threadIdx.x] = 0.f;
  __syncthreads();
  dot = wave_sum(dot); nsq = wave_sum(nsq);
  if ((threadIdx.x & 63) == 0) { atomicAdd(&red[0], dot); atomicAdd(&red[1], nsq); }
  __syncthreads();
  if (threadIdx.x == 0) atomicAdd(&acc[9], red[0] / fmaxf(sqrtf(red[1]), 1e-12f));
}

__global__ void k_final(const float* __restrict__ s1g, const float* __restrict__ s2g,
                        const float* __restrict__ cntg, const float* __restrict__ acc,
                        float* __restrict__ out) {
  int t = threadIdx.x;
  float vsum = 0.f, vcnt = 0.f;
  if (t < BN*KK) {
    int k = t % KK;
    float count = cntg[t];
    float nc = fmaxf(count, 1.f);
    float var = 0.f;
#pragma unroll
    for (int c = 0; c < CC; ++c) {
      float m1 = s1g[t*CC + c] / nc;
      var += s2g[t*CC + c] / nc - m1 * m1;
    }
    var *= (1.f / CC);
    if (k > 0 && count >= 25.f) { vsum = var; vcnt = 1.f; }
  }
  __shared__ float red[2];
  if (t < 2) red[t] = 0.f;
  __syncthreads();
  vsum = wave_sum(vsum); vcnt = wave_sum(vcnt);
  if ((t & 63) == 0) { atomicAdd(&red[0], vsum); atomicAdd(&red[1], vcnt); }
  __syncthreads();
  if (t == 0) {
    float l_distill = acc[1] * (1.f / NPIX);
    float bcnt = acc[3];
    float l_bpl = (bcnt > 0.f) ? acc[2] / fmaxf(bcnt, 1.f) : 0.f;
    float l_align = acc[5] * (1.f / (BN*HH*(WW-1))) + acc[6] * (1.f / (BN*(HH-1)*WW));
    float l_ent = acc[4] * (1.f / NPIX);
    float l_ib = 0.5f * (acc[7] * (1.f / (BN*(HH-1)*WW)) + acc[8] * (1.f / (BN*HH*(WW-1))));
    float l_proto = -acc[9] * (1.f / NPIX);
    float l_iu = red[0] / fmaxf(red[1], 1.f);
    out[0] = 1.0f*l_distill + 0.5f*l_bpl + 5.0f*l_align + 0.5f*l_proto +
             0.3f*l_ent + 0.5f*l_iu + 0.5f*l_ib;
  }
}

extern "C" void kernel_launch(void* const* d_in, const int* in_sizes, int n_in,
                              void* d_out, int out_size, void* d_ws, size_t ws_size,
                              hipStream_t stream) {
  (void)in_sizes; (void)n_in; (void)out_size; (void)ws_size;
  const float* logits = (const float*)d_in[0];
  const float* cause  = (const float*)d_in[1];
  const float* feats  = (const float*)d_in[2];
  const float* depth  = (const float*)d_in[3];
  const int*   inst   = (const int*)d_in[4];
  float* ws = (float*)d_ws;
  float* acc = ws + OFF_ACC;
  float* s1  = ws + OFF_S1;
  float* s2  = ws + OFF_S2;
  float* cnt = ws + OFF_CNT;
  float* nsq8 = ws + OFF_NSQ8;
  float* ce  = ws + OFF_CE;
  float* Pp  = ws + OFF_PP;
  float* Qp  = ws + OFF_QP;
  unsigned char* lab = (unsigned char*)(ws + OFF_LAB);
  unsigned short* probs = (unsigned short*)(ws + OFF_PROBS);
  unsigned char* fbf = (unsigned char*)(ws + OFF_FBF);
  unsigned char* wbf = (unsigned char*)(ws + OFF_WBF);
  float* out = (float*)d_out;

  k_zero<<<(ZERO_N + 255) / 256, 256, 0, stream>>>(ws, ZERO_N);
  k_big<<<800, 256, 0, stream>>>(feats, logits, cause, depth, fbf, nsq8, lab, ce,
                                 probs, wbf, acc);
  k_mainB<<<400, 256, 0, stream>>>(nsq8, wbf);
  k_gemmtail<<<GEMMB + TAILB, 256, 0, stream>>>(fbf, wbf, Pp, Qp, probs, depth, inst,
                                                lab, ce, acc, s1, s2, cnt);
  k_pfinal<<<BN * CC, 256, 0, stream>>>(Pp, Qp, acc);
  k_final<<<1, 256, 0, stream>>>(s1, s2, cnt, acc, out);
}